// Round 2
// baseline (2391.563 us; speedup 1.0000x reference)
//
#include <hip/hip_runtime.h>
#include <hip/hip_fp16.h>

#define NB 8
#define NPTS 4096
#define NS 1024
#define NK 32
#define NM (NB*NS*NK)   // 262144 grouped points

__device__ __forceinline__ float bf2f(unsigned short u){ return __uint_as_float(((unsigned)u)<<16); }
__device__ __forceinline__ unsigned short f2bf(float f){
  unsigned u = __float_as_uint(f);
  u = u + 0x7fffu + ((u>>16)&1u);   // RNE
  return (unsigned short)(u>>16);
}
__device__ __forceinline__ unsigned long long umax64(unsigned long long a, unsigned long long b){ return a>b?a:b; }
__device__ __forceinline__ unsigned long long umin64(unsigned long long a, unsigned long long b){ return a<b?a:b; }

// Runtime dtype detection: read first 64 ushorts of pc1. If the tensor is
// really float32, half of those are f32 low-mantissa halves -> decoded as
// bf16 they are huge/denormal with P~0.84 each (or exactly 0 if the f32
// values are bf16-rounded). True bf16 N(0,1) data decodes sane and nonzero.
// Block-uniform -> one scalar branch per kernel.
__device__ __forceinline__ bool detect_f32(const unsigned short* __restrict__ u){
  int huge_=0, zero_=0;
  #pragma unroll
  for (int i=0;i<64;i++){
    unsigned short w = u[i];
    if ((w & 0x7fffu) == 0) { zero_++; continue; }
    float a = fabsf(bf2f(w));
    if (a > 1e6f || a < 1e-6f) huge_++;
  }
  return (huge_ >= 8) || (zero_ >= 24);
}

__device__ __forceinline__ float ldin(const void* p, size_t i, bool f32){
  if (f32) return ((const float*)p)[i];
  else     return bf2f(((const unsigned short*)p)[i]);
}

// ---------------------------------------------------------------------------
// FPS: one block per batch. dist[] in registers (4 pts/thread), coords in LDS.
// Key = (dist_bits<<32) | (NPTS-1-n): max-reduce -> largest dist, tie -> lowest n
// (np.argmax first-max semantics). Distance math in __f*_rn f32, numpy order.
// ---------------------------------------------------------------------------
__global__ __launch_bounds__(1024) void fps_kernel(const void* __restrict__ pc1,
                                                   int* __restrict__ fps_out){
  __shared__ __align__(16) float cp[NPTS][3];
  __shared__ unsigned long long part[2][16];
  int b = blockIdx.x;
  int t = threadIdx.x;
  const bool f32 = detect_f32((const unsigned short*)pc1);
  float px[4],py[4],pz[4],dist[4];
  if (f32){
    const float* base = (const float*)pc1 + (size_t)b*3*NPTS;
    for (int i=t;i<NPTS;i+=1024){
      cp[i][0]=base[i]; cp[i][1]=base[NPTS+i]; cp[i][2]=base[2*NPTS+i];
    }
    #pragma unroll
    for(int i=0;i<4;i++){
      int n = t + 1024*i;
      px[i]=base[n]; py[i]=base[NPTS+n]; pz[i]=base[2*NPTS+n];
    }
  } else {
    const unsigned short* base = (const unsigned short*)pc1 + (size_t)b*3*NPTS;
    for (int i=t;i<NPTS;i+=1024){
      cp[i][0]=bf2f(base[i]); cp[i][1]=bf2f(base[NPTS+i]); cp[i][2]=bf2f(base[2*NPTS+i]);
    }
    #pragma unroll
    for(int i=0;i<4;i++){
      int n = t + 1024*i;
      px[i]=bf2f(base[n]); py[i]=bf2f(base[NPTS+n]); pz[i]=bf2f(base[2*NPTS+n]);
    }
  }
  #pragma unroll
  for(int i=0;i<4;i++) dist[i]=1e10f;
  __syncthreads();
  int far = 0;
  for (int it=0; it<NS; it++){
    if (t==0) fps_out[b*NS + it] = far;
    float cx=cp[far][0], cy=cp[far][1], cz=cp[far][2];
    unsigned long long best=0ull;
    #pragma unroll
    for(int i=0;i<4;i++){
      int n = t + 1024*i;
      float dx=__fsub_rn(px[i],cx), dy=__fsub_rn(py[i],cy), dz=__fsub_rn(pz[i],cz);
      float d = __fadd_rn(__fadd_rn(__fmul_rn(dx,dx),__fmul_rn(dy,dy)),__fmul_rn(dz,dz));
      float nd = fminf(dist[i], d);
      dist[i]=nd;
      unsigned long long key = ((unsigned long long)__float_as_uint(nd)<<32) | (unsigned)(NPTS-1-n);
      best = umax64(best,key);
    }
    #pragma unroll
    for(int off=32;off;off>>=1) best = umax64(best, __shfl_xor(best,off,64));
    if ((t&63)==0) part[it&1][t>>6]=best;
    __syncthreads();
    unsigned long long w = part[it&1][0];
    #pragma unroll
    for(int i=1;i<16;i++) w = umax64(w, part[it&1][i]);
    far = NPTS-1 - (int)(w & 0xffffffffu);
  }
}

// ---------------------------------------------------------------------------
// kNN: one block per (b,s). xyz staged in LDS. Each thread holds 16 u64 keys
// (ordered_dist_bits<<32 | n); 32 rounds of block-min + mask winner.
// ---------------------------------------------------------------------------
__global__ __launch_bounds__(256) void knn_kernel(const void* __restrict__ pc1,
                                                  const int* __restrict__ fps_idx,
                                                  float* __restrict__ new_xyz,
                                                  int* __restrict__ knn_idx){
  __shared__ float xs[NPTS], ys[NPTS], zs[NPTS];
  __shared__ unsigned long long part[2][4];
  int blk = blockIdx.x;
  int b = blk >> 10;
  int t = threadIdx.x;
  const bool f32 = detect_f32((const unsigned short*)pc1);
  if (f32){
    const float* base = (const float*)pc1 + (size_t)b*3*NPTS;
    for (int i=t;i<NPTS;i+=256){ xs[i]=base[i]; ys[i]=base[NPTS+i]; zs[i]=base[2*NPTS+i]; }
  } else {
    const unsigned short* base = (const unsigned short*)pc1 + (size_t)b*3*NPTS;
    for (int i=t;i<NPTS;i+=256){ xs[i]=bf2f(base[i]); ys[i]=bf2f(base[NPTS+i]); zs[i]=bf2f(base[2*NPTS+i]); }
  }
  __syncthreads();
  int n0 = fps_idx[blk];
  float qx=xs[n0], qy=ys[n0], qz=zs[n0];
  if (t==0){ new_xyz[(size_t)blk*3]=qx; new_xyz[(size_t)blk*3+1]=qy; new_xyz[(size_t)blk*3+2]=qz; }
  float qn = __fadd_rn(__fadd_rn(__fmul_rn(qx,qx),__fmul_rn(qy,qy)),__fmul_rn(qz,qz));
  unsigned long long keys[16];
  #pragma unroll
  for(int i=0;i<16;i++){
    int n = t + 256*i;
    float x=xs[n], y=ys[n], z=zs[n];
    float pn = __fadd_rn(__fadd_rn(__fmul_rn(x,x),__fmul_rn(y,y)),__fmul_rn(z,z));
    float dt = __fadd_rn(__fadd_rn(__fmul_rn(qx,x),__fmul_rn(qy,y)),__fmul_rn(qz,z));
    float d  = __fsub_rn(__fadd_rn(qn,pn), __fmul_rn(2.f,dt));
    unsigned u = __float_as_uint(d);
    u = (u & 0x80000000u) ? ~u : (u | 0x80000000u);   // order-preserving map
    keys[i] = ((unsigned long long)u<<32) | (unsigned)n;
  }
  for (int r=0;r<NK;r++){
    unsigned long long best = keys[0];
    #pragma unroll
    for(int i=1;i<16;i++) best = umin64(best, keys[i]);
    #pragma unroll
    for(int off=32;off;off>>=1) best = umin64(best, __shfl_xor(best, off, 64));
    if ((t&63)==0) part[r&1][t>>6] = best;
    __syncthreads();
    unsigned long long win = part[r&1][0];
    #pragma unroll
    for(int wv2=1;wv2<4;wv2++) win = umin64(win, part[r&1][wv2]);
    int n = (int)(win & 0xffffffffu);
    if (t==0) knn_idx[(size_t)blk*NK + r] = n;
    if ((n & 255) == t) keys[n>>8] = ~0ull;   // owner masks winner out
  }
}

// ---------------------------------------------------------------------------
// Conv layer: tile 128 points x 128 out-channels, 256 threads, 8x8 register
// blocking. LAYER==1 gathers [dxyz | feats] on the fly; LAYER 2/3 read fp16 H,
// apply instance-norm + relu of previous layer. Stats -> 2 f32 atomics/block.
// Biases b1..b3 omitted: cancel exactly under InstanceNorm(affine=False).
// ---------------------------------------------------------------------------
template<int LAYER>
__global__ __launch_bounds__(256) void conv_kernel(
    const void* __restrict__ pc1,
    const void* __restrict__ feats,
    const int* __restrict__ knn_idx,
    const float* __restrict__ new_xyz,
    const __half* __restrict__ Hin,
    const float* __restrict__ mu,
    const float* __restrict__ rs,
    const void* __restrict__ W,
    __half* __restrict__ Hout,
    float* __restrict__ gs1,
    float* __restrict__ gs2)
{
  constexpr int KC = (LAYER==1)?131:128;
  __shared__ __align__(16) float hs[128][36];
  __shared__ __align__(16) float wt[128][36];
  __shared__ float red[16][132];
  __shared__ int nidx[128];
  __shared__ float cxyz[4][3];
  int blk = blockIdx.x;
  int m0 = blk*128;
  int b = m0 >> 15;               // 32768 grouped points per batch
  int t = threadIdx.x;
  const bool f32 = detect_f32((const unsigned short*)pc1);
  if (LAYER==1){
    if (t<128) nidx[t] = knn_idx[m0+t];
    if (t<12)  cxyz[t/3][t%3] = new_xyz[(size_t)(m0>>5)*3 + t]; // 4 centers/block
  }
  __syncthreads();
  float acc[8][8];
  #pragma unroll
  for(int i=0;i<8;i++)
    #pragma unroll
    for(int j=0;j<8;j++) acc[i][j]=0.f;
  int tx = t & 15, pg = t >> 4;
  for (int c0=0;c0<KC;c0+=32){
    int w = KC - c0; if (w>32) w=32;
    { // stage W chunk as f32: wt[o][j]
      int o = t>>1; int jb = (t&1)*16;
      #pragma unroll
      for(int jj=0;jj<16;jj++){
        int j = jb+jj;
        if (j<w) wt[o][j] = ldin(W, (size_t)o*KC + c0 + j, f32);
      }
    }
    { // stage h chunk: hs[p][j]
      int p = t & 127; int hi = t>>7;
      #pragma unroll
      for(int jj=0;jj<16;jj++){
        int j = hi*16 + jj;
        if (j<w){
          int c = c0+j; float v;
          if (LAYER==1){
            int n = nidx[p];
            if (c<3) v = ldin(pc1, ((size_t)b*3 + c)*NPTS + n, f32) - cxyz[p>>5][c];
            else     v = ldin(feats, ((size_t)b*128 + (c-3))*NPTS + n, f32);
          } else {
            int bo = b*128 + c;
            float raw = __half2float(Hin[(size_t)(m0+p)*128 + c]);
            v = (raw - mu[bo])*rs[bo];
            v = v>0.f ? v : 0.f;
          }
          hs[p][j] = v;
        }
      }
    }
    __syncthreads();
    int w4 = w & ~3;
    for (int j=0;j<w4;j+=4){
      float4 av[8], wv[8];
      #pragma unroll
      for(int i=0;i<8;i++) av[i] = *(const float4*)&hs[pg+16*i][j];
      #pragma unroll
      for(int k=0;k<8;k++) wv[k] = *(const float4*)&wt[tx+16*k][j];
      #pragma unroll
      for(int i=0;i<8;i++){
        #pragma unroll
        for(int k=0;k<8;k++){
          acc[i][k] = fmaf(av[i].x, wv[k].x, acc[i][k]);
          acc[i][k] = fmaf(av[i].y, wv[k].y, acc[i][k]);
          acc[i][k] = fmaf(av[i].z, wv[k].z, acc[i][k]);
          acc[i][k] = fmaf(av[i].w, wv[k].w, acc[i][k]);
        }
      }
    }
    for (int j=w4;j<w;j++){   // tail (layer1 last chunk, w=3)
      float av[8], wv[8];
      #pragma unroll
      for(int i=0;i<8;i++) av[i]=hs[pg+16*i][j];
      #pragma unroll
      for(int k=0;k<8;k++) wv[k]=wt[tx+16*k][j];
      #pragma unroll
      for(int i=0;i<8;i++)
        #pragma unroll
        for(int k=0;k<8;k++)
          acc[i][k]=fmaf(av[i],wv[k],acc[i][k]);
    }
    __syncthreads();
  }
  // epilogue: write fp16 H + per-(b,o) stats
  float s1l[8], s2l[8];
  #pragma unroll
  for(int k=0;k<8;k++){
    int o = tx + 16*k;
    float s1=0.f, s2=0.f;
    #pragma unroll
    for(int i=0;i<8;i++){
      float v = acc[i][k];
      Hout[(size_t)(m0 + pg + 16*i)*128 + o] = __float2half(v);
      s1 += v; s2 = fmaf(v,v,s2);
    }
    s1l[k]=s1; s2l[k]=s2;
  }
  #pragma unroll
  for(int k=0;k<8;k++) red[pg][tx+16*k] = s1l[k];
  __syncthreads();
  if (t < 128){
    float a=0.f;
    #pragma unroll
    for(int g=0; g<16; g++) a += red[g][t];
    unsafeAtomicAdd(&gs1[b*128 + t], a);
  }
  __syncthreads();
  #pragma unroll
  for(int k=0;k<8;k++) red[pg][tx+16*k] = s2l[k];
  __syncthreads();
  if (t < 128){
    float a=0.f;
    #pragma unroll
    for(int g=0;g<16;g++) a += red[g][t];
    unsafeAtomicAdd(&gs2[b*128 + t], a);
  }
}

__global__ void stats_finalize(const float* __restrict__ gs1, const float* __restrict__ gs2,
                               float* __restrict__ mu, float* __restrict__ rs){
  int i = blockIdx.x*256 + threadIdx.x;   // 1024 = B*128
  const float inv = 1.0f/32768.0f;
  float m = gs1[i]*inv;
  float v = gs2[i]*inv - m*m;
  mu[i] = m;
  rs[i] = rsqrtf(v + 1e-5f);
}

// ---------------------------------------------------------------------------
// Final: per (b,s): norm+relu layer3, max over K, fc 128->3, out [B,3,S]
// ---------------------------------------------------------------------------
__global__ __launch_bounds__(128) void final_kernel(
    const void* __restrict__ pc1,
    const __half* __restrict__ H, const float* __restrict__ mu, const float* __restrict__ rs,
    const void* __restrict__ fc_w, const void* __restrict__ fc_b,
    void* __restrict__ outv)
{
  int blk = blockIdx.x;       // b*1024+s
  int b = blk>>10, s = blk & 1023;
  int o = threadIdx.x;
  const bool f32 = detect_f32((const unsigned short*)pc1);
  int bo = b*128 + o;
  float mu_ = mu[bo], rs_ = rs[bo];
  const __half* hp = H + (size_t)blk*NK*128 + o;
  float m = -1e30f;
  #pragma unroll 4
  for(int k=0;k<NK;k++){
    float v = (__half2float(hp[(size_t)k*128]) - mu_)*rs_;
    m = fmaxf(m, v);
  }
  m = fmaxf(m, 0.f);   // max_k relu(x_k) == relu(max_k x_k)
  __shared__ float mv[128];
  mv[o] = m;
  __syncthreads();
  if (o<3){
    float acc = ldin(fc_b, o, f32);
    for(int c=0;c<128;c++) acc = fmaf(ldin(fc_w, (size_t)o*128+c, f32), mv[c], acc);
    size_t oi = ((size_t)b*3 + o)*NS + s;
    if (f32) ((float*)outv)[oi] = acc;
    else     ((unsigned short*)outv)[oi] = f2bf(acc);
  }
}

// ---------------------------------------------------------------------------
extern "C" void kernel_launch(void* const* d_in, const int* in_sizes, int n_in,
                              void* d_out, int out_size, void* d_ws, size_t ws_size,
                              hipStream_t stream){
  const void* pc1   = d_in[0];
  const void* feats = d_in[1];
  const void* W1    = d_in[2];
  // d_in[3] = b1 (cancels under instance norm)
  const void* W2    = d_in[4];
  // d_in[5] = b2
  const void* W3    = d_in[6];
  // d_in[7] = b3
  const void* fcw   = d_in[8];
  const void* fcb   = d_in[9];
  char* ws = (char*)d_ws;
  // workspace layout (bytes)
  int*    fps  = (int*)  (ws + 0);          // 8192 * 4        = 32768
  float*  nxyz = (float*)(ws + 32768);      // 8192 * 3 * 4    = 98304
  int*    knn  = (int*)  (ws + 131072);     // 262144 * 4      = 1048576
  float*  s1   = (float*)(ws + 1179648);    // 1024 * 4
  float*  s2   = (float*)(ws + 1183744);    // 1024 * 4
  float*  mub  = (float*)(ws + 1187840);    // 3 * 1024 * 4
  float*  rsb  = (float*)(ws + 1200128);    // 3 * 1024 * 4
  __half* Ha   = (__half*)(ws + 1212416);   // 33554432 * 2 = 67108864
  __half* Hb   = (__half*)(ws + 68321280);  // 67108864 ; total 135430144 B

  fps_kernel<<<NB, 1024, 0, stream>>>(pc1, fps);
  knn_kernel<<<NB*NS, 256, 0, stream>>>(pc1, fps, nxyz, knn);

  hipMemsetAsync(s1, 0, 8192, stream);  // zeros s1+s2 (contiguous)
  conv_kernel<1><<<NM/128, 256, 0, stream>>>(pc1, feats, knn, nxyz,
      (const __half*)nullptr, (const float*)nullptr, (const float*)nullptr, W1, Ha, s1, s2);
  stats_finalize<<<4,256,0,stream>>>(s1, s2, mub, rsb);

  hipMemsetAsync(s1, 0, 8192, stream);
  conv_kernel<2><<<NM/128, 256, 0, stream>>>(pc1, feats, knn, nxyz,
      Ha, mub, rsb, W2, Hb, s1, s2);
  stats_finalize<<<4,256,0,stream>>>(s1, s2, mub+1024, rsb+1024);

  hipMemsetAsync(s1, 0, 8192, stream);
  conv_kernel<3><<<NM/128, 256, 0, stream>>>(pc1, feats, knn, nxyz,
      Hb, mub+1024, rsb+1024, W3, Ha, s1, s2);
  stats_finalize<<<4,256,0,stream>>>(s1, s2, mub+2048, rsb+2048);

  final_kernel<<<NB*NS, 128, 0, stream>>>(pc1, Ha, mub+2048, rsb+2048, fcw, fcb, d_out);
}

// Round 3
// 1744.958 us; speedup vs baseline: 1.3706x; 1.3706x over previous
//
#include <hip/hip_runtime.h>
#include <hip/hip_fp16.h>

#define NB 8
#define NPTS 4096
#define NS 1024
#define NK 32
#define NM (NB*NS*NK)   // 262144 grouped points

typedef _Float16 f16x8 __attribute__((ext_vector_type(8)));
typedef float    f32x4 __attribute__((ext_vector_type(4)));

__device__ __forceinline__ float bf2f(unsigned short u){ return __uint_as_float(((unsigned)u)<<16); }
__device__ __forceinline__ unsigned short f2bf(float f){
  unsigned u = __float_as_uint(f);
  u = u + 0x7fffu + ((u>>16)&1u);   // RNE
  return (unsigned short)(u>>16);
}
__device__ __forceinline__ unsigned long long umax64(unsigned long long a, unsigned long long b){ return a>b?a:b; }
__device__ __forceinline__ unsigned long long umin64(unsigned long long a, unsigned long long b){ return a<b?a:b; }

// Runtime dtype detection (block-uniform scalar branch): f32 data read as bf16
// halves decodes huge/denormal or exact-zero; true bf16 N(0,1) does not.
__device__ __forceinline__ bool detect_f32(const unsigned short* __restrict__ u){
  int huge_=0, zero_=0;
  #pragma unroll
  for (int i=0;i<64;i++){
    unsigned short w = u[i];
    if ((w & 0x7fffu) == 0) { zero_++; continue; }
    float a = fabsf(bf2f(w));
    if (a > 1e6f || a < 1e-6f) huge_++;
  }
  return (huge_ >= 8) || (zero_ >= 24);
}
__device__ __forceinline__ float ldin(const void* p, size_t i, bool f32){
  if (f32) return ((const float*)p)[i];
  else     return bf2f(((const unsigned short*)p)[i]);
}

// ---------------------------------------------------------------------------
// FPS: one block/batch, 256 threads, 16 contiguous pts/thread in registers.
// Chain/iter: part-read + cp[far] LDS read + 16-pt update + 6-lvl u64 shfl
// + 1 barrier (parity partials). Key = dist_bits<<32 | (4095-n): max ->
// largest dist, tie -> lowest n (np.argmax first-max). __f*_rn math, np order.
// ---------------------------------------------------------------------------
__global__ __launch_bounds__(256) void fps_kernel(const void* __restrict__ pc1,
                                                  int* __restrict__ fps_out){
  __shared__ float cpx[NPTS], cpy[NPTS], cpz[NPTS];
  __shared__ unsigned long long part[2][4];
  int b = blockIdx.x, t = threadIdx.x;
  const bool f32 = detect_f32((const unsigned short*)pc1);
  const size_t base = (size_t)b*3*NPTS;
  for (int i=t;i<NPTS;i+=256){
    cpx[i] = ldin(pc1, base+i, f32);
    cpy[i] = ldin(pc1, base+NPTS+i, f32);
    cpz[i] = ldin(pc1, base+2*NPTS+i, f32);
  }
  __syncthreads();
  float px[16],py[16],pz[16],dist[16];
  #pragma unroll
  for (int i=0;i<16;i++){
    int n = t*16+i;
    px[i]=cpx[n]; py[i]=cpy[n]; pz[i]=cpz[n];
    dist[i]=1e10f;
  }
  int far = 0;
  int w = t>>6, lane = t&63;
  for (int it=0; it<NS; it++){
    if (t==0) fps_out[b*NS+it] = far;
    float cx=cpx[far], cy=cpy[far], cz=cpz[far];
    float bl = -1.f; int bn = 0;
    #pragma unroll
    for (int i=0;i<16;i++){
      float dx=__fsub_rn(px[i],cx), dy=__fsub_rn(py[i],cy), dz=__fsub_rn(pz[i],cz);
      float d = __fadd_rn(__fadd_rn(__fmul_rn(dx,dx),__fmul_rn(dy,dy)),__fmul_rn(dz,dz));
      float nd = fminf(dist[i], d);
      dist[i]=nd;
      if (nd > bl){ bl = nd; bn = t*16+i; }   // strict >, ascending i: first max
    }
    unsigned long long key = ((unsigned long long)__float_as_uint(bl)<<32) | (unsigned)(NPTS-1-bn);
    #pragma unroll
    for (int off=32;off;off>>=1) key = umax64(key, __shfl_xor(key, off, 64));
    if (lane==0) part[it&1][w] = key;
    __syncthreads();
    unsigned long long m = umax64(umax64(part[it&1][0],part[it&1][1]),
                                  umax64(part[it&1][2],part[it&1][3]));
    far = NPTS-1 - (int)(m & 0xffffffffu);
  }
}

// ---------------------------------------------------------------------------
// kNN: unchanged from passing round.
// ---------------------------------------------------------------------------
__global__ __launch_bounds__(256) void knn_kernel(const void* __restrict__ pc1,
                                                  const int* __restrict__ fps_idx,
                                                  float* __restrict__ new_xyz,
                                                  int* __restrict__ knn_idx){
  __shared__ float xs[NPTS], ys[NPTS], zs[NPTS];
  __shared__ unsigned long long part[2][4];
  int blk = blockIdx.x;
  int b = blk >> 10;
  int t = threadIdx.x;
  const bool f32 = detect_f32((const unsigned short*)pc1);
  if (f32){
    const float* base = (const float*)pc1 + (size_t)b*3*NPTS;
    for (int i=t;i<NPTS;i+=256){ xs[i]=base[i]; ys[i]=base[NPTS+i]; zs[i]=base[2*NPTS+i]; }
  } else {
    const unsigned short* base = (const unsigned short*)pc1 + (size_t)b*3*NPTS;
    for (int i=t;i<NPTS;i+=256){ xs[i]=bf2f(base[i]); ys[i]=bf2f(base[NPTS+i]); zs[i]=bf2f(base[2*NPTS+i]); }
  }
  __syncthreads();
  int n0 = fps_idx[blk];
  float qx=xs[n0], qy=ys[n0], qz=zs[n0];
  if (t==0){ new_xyz[(size_t)blk*3]=qx; new_xyz[(size_t)blk*3+1]=qy; new_xyz[(size_t)blk*3+2]=qz; }
  float qn = __fadd_rn(__fadd_rn(__fmul_rn(qx,qx),__fmul_rn(qy,qy)),__fmul_rn(qz,qz));
  unsigned long long keys[16];
  #pragma unroll
  for(int i=0;i<16;i++){
    int n = t + 256*i;
    float x=xs[n], y=ys[n], z=zs[n];
    float pn = __fadd_rn(__fadd_rn(__fmul_rn(x,x),__fmul_rn(y,y)),__fmul_rn(z,z));
    float dt = __fadd_rn(__fadd_rn(__fmul_rn(qx,x),__fmul_rn(qy,y)),__fmul_rn(qz,z));
    float d  = __fsub_rn(__fadd_rn(qn,pn), __fmul_rn(2.f,dt));
    unsigned u = __float_as_uint(d);
    u = (u & 0x80000000u) ? ~u : (u | 0x80000000u);   // order-preserving map
    keys[i] = ((unsigned long long)u<<32) | (unsigned)n;
  }
  for (int r=0;r<NK;r++){
    unsigned long long best = keys[0];
    #pragma unroll
    for(int i=1;i<16;i++) best = umin64(best, keys[i]);
    #pragma unroll
    for(int off=32;off;off>>=1) best = umin64(best, __shfl_xor(best, off, 64));
    if ((t&63)==0) part[r&1][t>>6] = best;
    __syncthreads();
    unsigned long long win = part[r&1][0];
    #pragma unroll
    for(int wv2=1;wv2<4;wv2++) win = umin64(win, part[r&1][wv2]);
    int n = (int)(win & 0xffffffffu);
    if (t==0) knn_idx[(size_t)blk*NK + r] = n;
    if ((n & 255) == t) keys[n>>8] = ~0ull;   // owner masks winner out
  }
}

// ---------------------------------------------------------------------------
// feats [B,128,N] (f32/bf16) -> G [B,N,136] fp16: slot 0..2 = 0 (dxyz later),
// 3..130 = feats, 131..135 = 0. Row stride 136 halves = 272 B (16B aligned).
// ---------------------------------------------------------------------------
__global__ __launch_bounds__(256) void feat_transpose(const void* __restrict__ feats,
                                                      const void* __restrict__ pc1,
                                                      _Float16* __restrict__ G){
  __shared__ float tile[128][65];
  const bool f32 = detect_f32((const unsigned short*)pc1);
  int blk = blockIdx.x;             // b*64 + ntile
  int b = blk>>6, n0 = (blk&63)*64;
  int t = threadIdx.x;
  #pragma unroll 4
  for (int i=0;i<32;i++){
    int idx = i*256 + t;
    int c = idx>>6, n = idx&63;
    tile[c][n] = ldin(feats, ((size_t)b*128 + c)*NPTS + n0 + n, f32);
  }
  __syncthreads();
  #pragma unroll 4
  for (int i=0;i<32;i++){
    int idx = i*256 + t;
    int n = idx>>7, c = idx&127;
    G[((size_t)b*NPTS + n0 + n)*136 + 3 + c] = (_Float16)tile[c][n];
  }
  if (t<64){
    size_t gb = ((size_t)b*NPTS + n0 + t)*136;
    G[gb]=(_Float16)0.f; G[gb+1]=(_Float16)0.f; G[gb+2]=(_Float16)0.f;
    #pragma unroll
    for (int c=131;c<136;c++) G[gb+c]=(_Float16)0.f;
  }
}

// ---------------------------------------------------------------------------
// MFMA conv: block = 128 pts x 128 outs, 4 waves at 64x64, K chunks of 32.
// mfma_f32_16x16x32_f16, f32 accumulate. A/B frags: m|n = lane&15,
// k = (lane>>4)*8 + j; C/D: col = lane&15, row = (lane>>4)*4 + reg.
// LAYER 1: A rows from G (gathered by knn) + dxyz, K padded 131->160.
// LAYER 2/3: A = relu((Hin - mu)*rs) from fp16 Hin.
// Stats (f32, pre-fp16-rounding) -> per-(b,o) atomics. Biases cancel under IN.
// ---------------------------------------------------------------------------
template<int LAYER>
__global__ __launch_bounds__(256) void conv_mfma(
    const void* __restrict__ pc1,
    const _Float16* __restrict__ G,
    const int* __restrict__ knn_idx,
    const float* __restrict__ new_xyz,
    const _Float16* __restrict__ Hin,
    const float* __restrict__ mu,
    const float* __restrict__ rs,
    const void* __restrict__ W,
    _Float16* __restrict__ Hout,
    float* __restrict__ gs1, float* __restrict__ gs2)
{
  constexpr int KC  = (LAYER==1)?131:128;
  constexpr int KCP = (LAYER==1)?160:128;
  __shared__ _Float16 hs[128][168];
  __shared__ _Float16 wt[128][40];
  __shared__ float red1[4][64], red2[4][64];
  __shared__ int   nidx[128];
  __shared__ float cxyz[4][3];
  __shared__ float smu[128], srs[128];
  int blk = blockIdx.x;
  int m0 = blk*128;
  int b  = m0 >> 15;
  int t  = threadIdx.x;
  const bool f32 = detect_f32((const unsigned short*)pc1);
  int w = t>>6, lane = t&63;
  int l16 = lane&15, q = lane>>4, q8 = q*8;
  int wr = (w&1)*64, wc = (w>>1)*64;

  if (LAYER==1){
    if (t<128) nidx[t] = knn_idx[m0+t];
    if (t<12)  cxyz[t/3][t%3] = new_xyz[(size_t)(m0>>5)*3 + t];
    __syncthreads();
    for (int u=t; u<128*17; u+=256){               // 17 x 8-half chunks/row
      int p = u/17, qq = u - p*17;
      const f16x8* src = (const f16x8*)(G + ((size_t)b*NPTS + nidx[p])*136 + qq*8);
      *(f16x8*)&hs[p][qq*8] = *src;
    }
    for (int u=t; u<128*3; u+=256){                // zero pad c in [136,160)
      int p = u/3, qq = u - p*3;
      uint4 z; z.x=z.y=z.z=z.w=0u;
      *(uint4*)&hs[p][136+qq*8] = z;
    }
    __syncthreads();
    if (t<128){
      int n = nidx[t];
      float cx = cxyz[t>>5][0], cy = cxyz[t>>5][1], cz = cxyz[t>>5][2];
      hs[t][0] = (_Float16)(ldin(pc1, ((size_t)b*3+0)*NPTS+n, f32) - cx);
      hs[t][1] = (_Float16)(ldin(pc1, ((size_t)b*3+1)*NPTS+n, f32) - cy);
      hs[t][2] = (_Float16)(ldin(pc1, ((size_t)b*3+2)*NPTS+n, f32) - cz);
    }
    __syncthreads();
  } else {
    if (t<128){ smu[t]=mu[b*128+t]; srs[t]=rs[b*128+t]; }
    __syncthreads();
    int p = t & 127, hi = t>>7;
    const _Float16* src = Hin + (size_t)(m0+p)*128 + hi*64;
    #pragma unroll
    for (int j=0;j<8;j++){
      f16x8 v = *(const f16x8*)(src + j*8);
      #pragma unroll
      for (int e=0;e<8;e++){
        int c = hi*64 + j*8 + e;
        float x = ((float)v[e] - smu[c]) * srs[c];
        hs[p][c] = (_Float16)(x > 0.f ? x : 0.f);
      }
    }
    __syncthreads();
  }

  f32x4 acc[4][4];
  #pragma unroll
  for (int i=0;i<4;i++)
    #pragma unroll
    for (int c=0;c<4;c++){ acc[i][c][0]=0.f; acc[i][c][1]=0.f; acc[i][c][2]=0.f; acc[i][c][3]=0.f; }

  for (int k0=0; k0<KCP; k0+=32){
    { // stage W chunk as fp16 (zero-padded past KC)
      int o = t>>1, half = t&1;
      #pragma unroll
      for (int jj=0;jj<16;jj++){
        int j = half*16 + jj, c = k0 + j;
        float wv = (c<KC) ? ldin(W, (size_t)o*KC + c, f32) : 0.f;
        wt[o][j] = (_Float16)wv;
      }
    }
    __syncthreads();
    f16x8 av[4], bv[4];
    #pragma unroll
    for (int i=0;i<4;i++) av[i] = *(const f16x8*)&hs[wr + i*16 + l16][k0 + q8];
    #pragma unroll
    for (int c=0;c<4;c++) bv[c] = *(const f16x8*)&wt[wc + c*16 + l16][q8];
    #pragma unroll
    for (int i=0;i<4;i++)
      #pragma unroll
      for (int c=0;c<4;c++)
        acc[i][c] = __builtin_amdgcn_mfma_f32_16x16x32_f16(av[i], bv[c], acc[i][c], 0,0,0);
    __syncthreads();
  }

  // epilogue: fp16 Hout + per-col stats (f32 acc values)
  #pragma unroll
  for (int c=0;c<4;c++){
    int o = wc + c*16 + l16;
    float s1=0.f, s2=0.f;
    #pragma unroll
    for (int i=0;i<4;i++){
      int row = wr + i*16 + q*4;
      #pragma unroll
      for (int r=0;r<4;r++){
        float v = acc[i][c][r];
        Hout[(size_t)(m0 + row + r)*128 + o] = (_Float16)v;
        s1 += v; s2 = fmaf(v,v,s2);
      }
    }
    s1 += __shfl_xor(s1, 16, 64); s1 += __shfl_xor(s1, 32, 64);
    s2 += __shfl_xor(s2, 16, 64); s2 += __shfl_xor(s2, 32, 64);
    if (q==0){ red1[w][c*16+l16] = s1; red2[w][c*16+l16] = s2; }
  }
  __syncthreads();
  if (t<128){
    int lo = t & 63, g = (t>>6)*2;
    unsafeAtomicAdd(&gs1[b*128+t], red1[g][lo] + red1[g+1][lo]);
    unsafeAtomicAdd(&gs2[b*128+t], red2[g][lo] + red2[g+1][lo]);
  }
}

__global__ void stats_finalize(const float* __restrict__ gs1, const float* __restrict__ gs2,
                               float* __restrict__ mu, float* __restrict__ rs){
  int i = blockIdx.x*256 + threadIdx.x;   // 1024 = B*128
  const float inv = 1.0f/32768.0f;
  float m = gs1[i]*inv;
  float v = gs2[i]*inv - m*m;
  mu[i] = m;
  rs[i] = rsqrtf(v + 1e-5f);
}

// ---------------------------------------------------------------------------
// Final: per (b,s): norm+relu layer3, max over K, fc 128->3, out [B,3,S]
// ---------------------------------------------------------------------------
__global__ __launch_bounds__(128) void final_kernel(
    const void* __restrict__ pc1,
    const _Float16* __restrict__ H, const float* __restrict__ mu, const float* __restrict__ rs,
    const void* __restrict__ fc_w, const void* __restrict__ fc_b,
    void* __restrict__ outv)
{
  int blk = blockIdx.x;       // b*1024+s
  int b = blk>>10, s = blk & 1023;
  int o = threadIdx.x;
  const bool f32 = detect_f32((const unsigned short*)pc1);
  int bo = b*128 + o;
  float mu_ = mu[bo], rs_ = rs[bo];
  const _Float16* hp = H + (size_t)blk*NK*128 + o;
  float m = -1e30f;
  #pragma unroll 4
  for(int k=0;k<NK;k++){
    float v = ((float)hp[(size_t)k*128] - mu_)*rs_;
    m = fmaxf(m, v);
  }
  m = fmaxf(m, 0.f);   // max_k relu(x_k) == relu(max_k x_k)
  __shared__ float mv[128];
  mv[o] = m;
  __syncthreads();
  if (o<3){
    float acc = ldin(fc_b, o, f32);
    for(int c=0;c<128;c++) acc = fmaf(ldin(fc_w, (size_t)o*128+c, f32), mv[c], acc);
    size_t oi = ((size_t)b*3 + o)*NS + s;
    if (f32) ((float*)outv)[oi] = acc;
    else     ((unsigned short*)outv)[oi] = f2bf(acc);
  }
}

// ---------------------------------------------------------------------------
extern "C" void kernel_launch(void* const* d_in, const int* in_sizes, int n_in,
                              void* d_out, int out_size, void* d_ws, size_t ws_size,
                              hipStream_t stream){
  const void* pc1   = d_in[0];
  const void* feats = d_in[1];
  const void* W1    = d_in[2];
  const void* W2    = d_in[4];
  const void* W3    = d_in[6];
  const void* fcw   = d_in[8];
  const void* fcb   = d_in[9];
  char* ws = (char*)d_ws;
  int*      fps  = (int*)     (ws + 0);          // 32768 B
  float*    nxyz = (float*)   (ws + 32768);      // 98304 B
  int*      knn  = (int*)     (ws + 131072);     // 1048576 B
  float*    s1   = (float*)   (ws + 1179648);    // 4096 B
  float*    s2   = (float*)   (ws + 1183744);    // 4096 B
  float*    mub  = (float*)   (ws + 1187840);    // 12288 B
  float*    rsb  = (float*)   (ws + 1200128);    // 12288 B
  _Float16* Ha   = (_Float16*)(ws + 1212416);    // 67108864 B
  _Float16* Hb   = (_Float16*)(ws + 68321280);   // 67108864 B (total 135430144)
  _Float16* G    = Hb;  // G (8.9 MB) aliases Hb: read only by conv1, Hb first written by conv2

  feat_transpose<<<NB*64, 256, 0, stream>>>(feats, pc1, G);
  fps_kernel<<<NB, 256, 0, stream>>>(pc1, fps);
  knn_kernel<<<NB*NS, 256, 0, stream>>>(pc1, fps, nxyz, knn);

  hipMemsetAsync(s1, 0, 8192, stream);  // zeros s1+s2 (contiguous)
  conv_mfma<1><<<NM/128, 256, 0, stream>>>(pc1, G, knn, nxyz,
      (const _Float16*)nullptr, (const float*)nullptr, (const float*)nullptr, W1, Ha, s1, s2);
  stats_finalize<<<4,256,0,stream>>>(s1, s2, mub, rsb);

  hipMemsetAsync(s1, 0, 8192, stream);
  conv_mfma<2><<<NM/128, 256, 0, stream>>>(pc1, G, knn, nxyz,
      Ha, mub, rsb, W2, Hb, s1, s2);
  stats_finalize<<<4,256,0,stream>>>(s1, s2, mub+1024, rsb+1024);

  hipMemsetAsync(s1, 0, 8192, stream);
  conv_mfma<3><<<NM/128, 256, 0, stream>>>(pc1, G, knn, nxyz,
      Hb, mub+1024, rsb+1024, W3, Ha, s1, s2);
  stats_finalize<<<4,256,0,stream>>>(s1, s2, mub+2048, rsb+2048);

  final_kernel<<<NB*NS, 128, 0, stream>>>(pc1, Ha, mub+2048, rsb+2048, fcw, fcb, d_out);
}

// Round 4
// 1448.722 us; speedup vs baseline: 1.6508x; 1.2045x over previous
//
#include <hip/hip_runtime.h>
#include <hip/hip_fp16.h>

#define NB 8
#define NPTS 4096
#define NS 1024
#define NK 32
#define NM (NB*NS*NK)   // 262144 grouped points

typedef _Float16 f16x8 __attribute__((ext_vector_type(8)));
typedef float    f32x4 __attribute__((ext_vector_type(4)));

__device__ __forceinline__ float bf2f(unsigned short u){ return __uint_as_float(((unsigned)u)<<16); }
__device__ __forceinline__ unsigned short f2bf(float f){
  unsigned u = __float_as_uint(f);
  u = u + 0x7fffu + ((u>>16)&1u);   // RNE
  return (unsigned short)(u>>16);
}
__device__ __forceinline__ unsigned long long umax64(unsigned long long a, unsigned long long b){ return a>b?a:b; }
__device__ __forceinline__ unsigned long long umin64(unsigned long long a, unsigned long long b){ return a<b?a:b; }

// ---- DPP wave64 reduce: row_shr 1/2/4/8 + row_bcast 15/31, result in lane 63.
// old = x so masked/invalid lanes contribute x (identity under max/min).
#define DPP_STEP_MAX(x, ctrl, rm) { \
  unsigned _t = (unsigned)__builtin_amdgcn_update_dpp((int)(x), (int)(x), (ctrl), (rm), 0xf, false); \
  (x) = ((x) > _t) ? (x) : _t; }
#define DPP_STEP_MIN(x, ctrl, rm) { \
  unsigned _t = (unsigned)__builtin_amdgcn_update_dpp((int)(x), (int)(x), (ctrl), (rm), 0xf, false); \
  (x) = ((x) < _t) ? (x) : _t; }

__device__ __forceinline__ unsigned wave_max_u32(unsigned x){
  DPP_STEP_MAX(x, 0x111, 0xf);   // row_shr:1
  DPP_STEP_MAX(x, 0x112, 0xf);   // row_shr:2
  DPP_STEP_MAX(x, 0x114, 0xf);   // row_shr:4
  DPP_STEP_MAX(x, 0x118, 0xf);   // row_shr:8
  DPP_STEP_MAX(x, 0x142, 0xa);   // row_bcast:15 -> rows 1,3
  DPP_STEP_MAX(x, 0x143, 0xc);   // row_bcast:31 -> rows 2,3
  return (unsigned)__builtin_amdgcn_readlane((int)x, 63);
}
__device__ __forceinline__ unsigned wave_min_u32(unsigned x){
  DPP_STEP_MIN(x, 0x111, 0xf);
  DPP_STEP_MIN(x, 0x112, 0xf);
  DPP_STEP_MIN(x, 0x114, 0xf);
  DPP_STEP_MIN(x, 0x118, 0xf);
  DPP_STEP_MIN(x, 0x142, 0xa);
  DPP_STEP_MIN(x, 0x143, 0xc);
  return (unsigned)__builtin_amdgcn_readlane((int)x, 63);
}

// Runtime dtype detection (block-uniform scalar branch): f32 data read as bf16
// halves decodes huge/denormal or exact-zero; true bf16 N(0,1) does not.
__device__ __forceinline__ bool detect_f32(const unsigned short* __restrict__ u){
  int huge_=0, zero_=0;
  #pragma unroll
  for (int i=0;i<64;i++){
    unsigned short w = u[i];
    if ((w & 0x7fffu) == 0) { zero_++; continue; }
    float a = fabsf(bf2f(w));
    if (a > 1e6f || a < 1e-6f) huge_++;
  }
  return (huge_ >= 8) || (zero_ >= 24);
}
__device__ __forceinline__ float ldin(const void* p, size_t i, bool f32){
  if (f32) return ((const float*)p)[i];
  else     return bf2f(((const unsigned short*)p)[i]);
}

// ---------------------------------------------------------------------------
// FPS: one block/batch, 512 threads, 8 contiguous pts/thread in registers.
// Per iter: cp[far] LDS read + 8-pt update (running strict-> argmax = first
// max) + DPP u32 max reduce + ballot/ctz/readlane index + 1 barrier + 8-key
// u64 scan. Key = dist<<32 | (4095-idx): max -> largest dist, tie lowest idx
// (np.argmax first-max). __f*_rn math, numpy order.
// ---------------------------------------------------------------------------
__global__ __launch_bounds__(512) void fps_kernel(const void* __restrict__ pc1,
                                                  int* __restrict__ fps_out){
  __shared__ __align__(16) float cpx[NPTS], cpy[NPTS], cpz[NPTS];
  __shared__ __align__(16) unsigned long long part[2][8];
  int b = blockIdx.x, t = threadIdx.x;
  const bool f32 = detect_f32((const unsigned short*)pc1);
  const size_t base = (size_t)b*3*NPTS;
  for (int i=t;i<NPTS;i+=512){
    cpx[i] = ldin(pc1, base+i, f32);
    cpy[i] = ldin(pc1, base+NPTS+i, f32);
    cpz[i] = ldin(pc1, base+2*NPTS+i, f32);
  }
  __syncthreads();
  float px[8],py[8],pz[8],dist[8];
  #pragma unroll
  for (int i=0;i<8;i++){
    int n = t*8+i;
    px[i]=cpx[n]; py[i]=cpy[n]; pz[i]=cpz[n];
    dist[i]=1e10f;
  }
  int far = 0;
  int w = t>>6, lane = t&63;
  for (int it=0; it<NS; it++){
    if (t==0) fps_out[b*NS+it] = far;
    float cx=cpx[far], cy=cpy[far], cz=cpz[far];
    unsigned bl = 0u; int bn = t*8;
    #pragma unroll
    for (int i=0;i<8;i++){
      float dx=__fsub_rn(px[i],cx), dy=__fsub_rn(py[i],cy), dz=__fsub_rn(pz[i],cz);
      float d = __fadd_rn(__fadd_rn(__fmul_rn(dx,dx),__fmul_rn(dy,dy)),__fmul_rn(dz,dz));
      float nd = fminf(dist[i], d);
      dist[i]=nd;
      unsigned nb = __float_as_uint(nd);        // non-negative: bits monotone
      if (nb > bl){ bl = nb; bn = t*8+i; }      // strict >, ascending i: first max
    }
    unsigned wm = wave_max_u32(bl);
    unsigned long long mk = __ballot(bl == wm);
    int l = __builtin_ctzll(mk);                // lowest lane = lowest chunk = lowest n
    int idx = __builtin_amdgcn_readlane(bn, l);
    if (lane==0) part[it&1][w] = ((unsigned long long)wm<<32) | (unsigned)(NPTS-1-idx);
    __syncthreads();
    const ulonglong2* pp = (const ulonglong2*)&part[it&1][0];
    ulonglong2 a=pp[0], b2=pp[1], c2=pp[2], d2=pp[3];
    unsigned long long m = umax64(umax64(umax64(a.x,a.y),umax64(b2.x,b2.y)),
                                  umax64(umax64(c2.x,c2.y),umax64(d2.x,d2.y)));
    far = NPTS-1 - (int)(m & 0xffffffffu);
  }
}

// ---------------------------------------------------------------------------
// kNN: one block per (b,s), 256 threads, 16 contiguous pts/thread as u32
// ordered-dist regs. 32 rounds: local strict-< argmin + DPP min + ballot +
// 1 barrier + 4-key u64 scan; winner masked via unrolled cndmask.
// ---------------------------------------------------------------------------
__global__ __launch_bounds__(256) void knn_kernel(const void* __restrict__ pc1,
                                                  const int* __restrict__ fps_idx,
                                                  float* __restrict__ new_xyz,
                                                  int* __restrict__ knn_idx){
  __shared__ __align__(16) float xs[NPTS], ys[NPTS], zs[NPTS];
  __shared__ __align__(16) unsigned long long part[2][4];
  int blk = blockIdx.x;
  int b = blk >> 10;
  int t = threadIdx.x;
  const bool f32 = detect_f32((const unsigned short*)pc1);
  if (f32){
    const float* base = (const float*)pc1 + (size_t)b*3*NPTS;
    for (int i=t;i<NPTS;i+=256){ xs[i]=base[i]; ys[i]=base[NPTS+i]; zs[i]=base[2*NPTS+i]; }
  } else {
    const unsigned short* base = (const unsigned short*)pc1 + (size_t)b*3*NPTS;
    for (int i=t;i<NPTS;i+=256){ xs[i]=bf2f(base[i]); ys[i]=bf2f(base[NPTS+i]); zs[i]=bf2f(base[2*NPTS+i]); }
  }
  __syncthreads();
  int n0 = fps_idx[blk];
  float qx=xs[n0], qy=ys[n0], qz=zs[n0];
  if (t==0){ new_xyz[(size_t)blk*3]=qx; new_xyz[(size_t)blk*3+1]=qy; new_xyz[(size_t)blk*3+2]=qz; }
  float qn = __fadd_rn(__fadd_rn(__fmul_rn(qx,qx),__fmul_rn(qy,qy)),__fmul_rn(qz,qz));
  unsigned db[16];
  #pragma unroll
  for(int i=0;i<16;i++){
    int n = t*16 + i;                            // contiguous chunk per thread
    float x=xs[n], y=ys[n], z=zs[n];
    float pn = __fadd_rn(__fadd_rn(__fmul_rn(x,x),__fmul_rn(y,y)),__fmul_rn(z,z));
    float dt = __fadd_rn(__fadd_rn(__fmul_rn(qx,x),__fmul_rn(qy,y)),__fmul_rn(qz,z));
    float d  = __fsub_rn(__fadd_rn(qn,pn), __fmul_rn(2.f,dt));
    unsigned u = __float_as_uint(d);
    db[i] = (u & 0x80000000u) ? ~u : (u | 0x80000000u);  // order-preserving map
  }
  int w = t>>6, lane = t&63;
  for (int r=0;r<NK;r++){
    unsigned bl = 0xFFFFFFFFu; int bn = t*16;
    #pragma unroll
    for (int i=0;i<16;i++){
      if (db[i] < bl){ bl = db[i]; bn = t*16+i; }   // strict <, first min
    }
    unsigned wm = wave_min_u32(bl);
    unsigned long long mk = __ballot(bl == wm);
    int l = __builtin_ctzll(mk);
    int idx = __builtin_amdgcn_readlane(bn, l);
    if (lane==0) part[r&1][w] = ((unsigned long long)wm<<32) | (unsigned)idx;
    __syncthreads();
    const ulonglong2* pp = (const ulonglong2*)&part[r&1][0];
    ulonglong2 a=pp[0], b2=pp[1];
    unsigned long long m = umin64(umin64(a.x,a.y), umin64(b2.x,b2.y));
    int n = (int)(m & 0xffffffffu);
    if (t==0) knn_idx[(size_t)blk*NK + r] = n;
    bool mine = ((n>>4) == t);
    #pragma unroll
    for (int i=0;i<16;i++)
      if (mine && ((n&15)==i)) db[i] = 0xFFFFFFFFu;   // cndmask form, no scratch
  }
}

// ---------------------------------------------------------------------------
// feats [B,128,N] (f32/bf16) -> G [B,N,136] fp16: slot 0..2 = 0 (dxyz later),
// 3..130 = feats, 131..135 = 0. Row stride 136 halves = 272 B (16B aligned).
// ---------------------------------------------------------------------------
__global__ __launch_bounds__(256) void feat_transpose(const void* __restrict__ feats,
                                                      const void* __restrict__ pc1,
                                                      _Float16* __restrict__ G){
  __shared__ float tile[128][65];
  const bool f32 = detect_f32((const unsigned short*)pc1);
  int blk = blockIdx.x;             // b*64 + ntile
  int b = blk>>6, n0 = (blk&63)*64;
  int t = threadIdx.x;
  #pragma unroll 4
  for (int i=0;i<32;i++){
    int idx = i*256 + t;
    int c = idx>>6, n = idx&63;
    tile[c][n] = ldin(feats, ((size_t)b*128 + c)*NPTS + n0 + n, f32);
  }
  __syncthreads();
  #pragma unroll 4
  for (int i=0;i<32;i++){
    int idx = i*256 + t;
    int n = idx>>7, c = idx&127;
    G[((size_t)b*NPTS + n0 + n)*136 + 3 + c] = (_Float16)tile[c][n];
  }
  if (t<64){
    size_t gb = ((size_t)b*NPTS + n0 + t)*136;
    G[gb]=(_Float16)0.f; G[gb+1]=(_Float16)0.f; G[gb+2]=(_Float16)0.f;
    #pragma unroll
    for (int c=131;c<136;c++) G[gb+c]=(_Float16)0.f;
  }
}

// ---------------------------------------------------------------------------
// MFMA conv: block = 128 pts x 128 outs, 4 waves at 64x64, K chunks of 32.
// mfma_f32_16x16x32_f16, f32 accumulate. A/B frags: m|n = lane&15,
// k = (lane>>4)*8 + j; C/D: col = lane&15, row = (lane>>4)*4 + reg.
// LAYER 1: A rows from G (gathered by knn) + dxyz, K padded 131->160.
// LAYER 2/3: A = relu((Hin - mu)*rs) fp16, packed f16x8 LDS writes; 48KB LDS.
// Stats (f32, pre-fp16-rounding) -> per-(b,o) atomics. Biases cancel under IN.
// ---------------------------------------------------------------------------
template<int LAYER>
__global__ __launch_bounds__(256) void conv_mfma(
    const void* __restrict__ pc1,
    const _Float16* __restrict__ G,
    const int* __restrict__ knn_idx,
    const float* __restrict__ new_xyz,
    const _Float16* __restrict__ Hin,
    const float* __restrict__ mu,
    const float* __restrict__ rs,
    const void* __restrict__ W,
    _Float16* __restrict__ Hout,
    float* __restrict__ gs1, float* __restrict__ gs2)
{
  constexpr int KC  = (LAYER==1)?131:128;
  constexpr int KCP = (LAYER==1)?160:128;
  constexpr int HSW = (LAYER==1)?168:136;   // LDS row stride (halves); 336B/272B both 16B-aligned, 2-way-max banks
  __shared__ __align__(16) _Float16 hs[128][HSW];
  __shared__ __align__(16) _Float16 wt[128][40];
  __shared__ float red1[4][64], red2[4][64];
  __shared__ int   nidx[128];
  __shared__ float cxyz[4][3];
  __shared__ float smu[128], srs[128];
  int blk = blockIdx.x;
  int m0 = blk*128;
  int b  = m0 >> 15;
  int t  = threadIdx.x;
  const bool f32 = detect_f32((const unsigned short*)pc1);
  int w = t>>6, lane = t&63;
  int l16 = lane&15, q = lane>>4, q8 = q*8;
  int wr = (w&1)*64, wc = (w>>1)*64;

  if (LAYER==1){
    if (t<128) nidx[t] = knn_idx[m0+t];
    if (t<12)  cxyz[t/3][t%3] = new_xyz[(size_t)(m0>>5)*3 + t];
    __syncthreads();
    for (int u=t; u<128*17; u+=256){               // 17 x 8-half chunks/row
      int p = u/17, qq = u - p*17;
      const f16x8* src = (const f16x8*)(G + ((size_t)b*NPTS + nidx[p])*136 + qq*8);
      *(f16x8*)&hs[p][qq*8] = *src;
    }
    for (int u=t; u<128*3; u+=256){                // zero pad c in [136,160)
      int p = u/3, qq = u - p*3;
      uint4 z; z.x=z.y=z.z=z.w=0u;
      *(uint4*)&hs[p][136+qq*8] = z;
    }
    __syncthreads();
    if (t<128){
      int n = nidx[t];
      float cx = cxyz[t>>5][0], cy = cxyz[t>>5][1], cz = cxyz[t>>5][2];
      hs[t][0] = (_Float16)(ldin(pc1, ((size_t)b*3+0)*NPTS+n, f32) - cx);
      hs[t][1] = (_Float16)(ldin(pc1, ((size_t)b*3+1)*NPTS+n, f32) - cy);
      hs[t][2] = (_Float16)(ldin(pc1, ((size_t)b*3+2)*NPTS+n, f32) - cz);
    }
    __syncthreads();
  } else {
    if (t<128){ smu[t]=mu[b*128+t]; srs[t]=rs[b*128+t]; }
    __syncthreads();
    int p = t & 127, hi = t>>7;
    const _Float16* src = Hin + (size_t)(m0+p)*128 + hi*64;
    #pragma unroll
    for (int j=0;j<8;j++){
      f16x8 v = *(const f16x8*)(src + j*8);
      f16x8 o;
      #pragma unroll
      for (int e=0;e<8;e++){
        int c = hi*64 + j*8 + e;
        float x = ((float)v[e] - smu[c]) * srs[c];
        o[e] = (_Float16)(x > 0.f ? x : 0.f);
      }
      *(f16x8*)&hs[p][hi*64 + j*8] = o;
    }
    __syncthreads();
  }

  f32x4 acc[4][4];
  #pragma unroll
  for (int i=0;i<4;i++)
    #pragma unroll
    for (int c=0;c<4;c++){ acc[i][c][0]=0.f; acc[i][c][1]=0.f; acc[i][c][2]=0.f; acc[i][c][3]=0.f; }

  for (int k0=0; k0<KCP; k0+=32){
    { // stage W chunk as fp16 (zero-padded past KC)
      int o = t>>1, half = t&1;
      f16x8 w0, w1;
      #pragma unroll
      for (int jj=0;jj<8;jj++){
        int c0 = k0 + half*16 + jj, c1 = c0 + 8;
        w0[jj] = (_Float16)((c0<KC) ? ldin(W, (size_t)o*KC + c0, f32) : 0.f);
        w1[jj] = (_Float16)((c1<KC) ? ldin(W, (size_t)o*KC + c1, f32) : 0.f);
      }
      *(f16x8*)&wt[o][half*16]     = w0;
      *(f16x8*)&wt[o][half*16 + 8] = w1;
    }
    __syncthreads();
    f16x8 av[4], bv[4];
    #pragma unroll
    for (int i=0;i<4;i++) av[i] = *(const f16x8*)&hs[wr + i*16 + l16][k0 + q8];
    #pragma unroll
    for (int c=0;c<4;c++) bv[c] = *(const f16x8*)&wt[wc + c*16 + l16][q8];
    #pragma unroll
    for (int i=0;i<4;i++)
      #pragma unroll
      for (int c=0;c<4;c++)
        acc[i][c] = __builtin_amdgcn_mfma_f32_16x16x32_f16(av[i], bv[c], acc[i][c], 0,0,0);
    __syncthreads();
  }

  // epilogue: fp16 Hout + per-col stats (f32 acc values)
  #pragma unroll
  for (int c=0;c<4;c++){
    int o = wc + c*16 + l16;
    float s1=0.f, s2=0.f;
    #pragma unroll
    for (int i=0;i<4;i++){
      int row = wr + i*16 + q*4;
      #pragma unroll
      for (int r=0;r<4;r++){
        float v = acc[i][c][r];
        Hout[(size_t)(m0 + row + r)*128 + o] = (_Float16)v;
        s1 += v; s2 = fmaf(v,v,s2);
      }
    }
    s1 += __shfl_xor(s1, 16, 64); s1 += __shfl_xor(s1, 32, 64);
    s2 += __shfl_xor(s2, 16, 64); s2 += __shfl_xor(s2, 32, 64);
    if (q==0){ red1[w][c*16+l16] = s1; red2[w][c*16+l16] = s2; }
  }
  __syncthreads();
  if (t<128){
    int lo = t & 63, g = (t>>6)*2;
    unsafeAtomicAdd(&gs1[b*128+t], red1[g][lo] + red1[g+1][lo]);
    unsafeAtomicAdd(&gs2[b*128+t], red2[g][lo] + red2[g+1][lo]);
  }
}

__global__ void stats_finalize(const float* __restrict__ gs1, const float* __restrict__ gs2,
                               float* __restrict__ mu, float* __restrict__ rs){
  int i = blockIdx.x*256 + threadIdx.x;   // 1024 = B*128
  const float inv = 1.0f/32768.0f;
  float m = gs1[i]*inv;
  float v = gs2[i]*inv - m*m;
  mu[i] = m;
  rs[i] = rsqrtf(v + 1e-5f);
}

// ---------------------------------------------------------------------------
// Final: per (b,s): norm+relu layer3, max over K, fc 128->3, out [B,3,S]
// ---------------------------------------------------------------------------
__global__ __launch_bounds__(128) void final_kernel(
    const void* __restrict__ pc1,
    const _Float16* __restrict__ H, const float* __restrict__ mu, const float* __restrict__ rs,
    const void* __restrict__ fc_w, const void* __restrict__ fc_b,
    void* __restrict__ outv)
{
  int blk = blockIdx.x;       // b*1024+s
  int b = blk>>10, s = blk & 1023;
  int o = threadIdx.x;
  const bool f32 = detect_f32((const unsigned short*)pc1);
  int bo = b*128 + o;
  float mu_ = mu[bo], rs_ = rs[bo];
  const _Float16* hp = H + (size_t)blk*NK*128 + o;
  float m = -1e30f;
  #pragma unroll 4
  for(int k=0;k<NK;k++){
    float v = ((float)hp[(size_t)k*128] - mu_)*rs_;
    m = fmaxf(m, v);
  }
  m = fmaxf(m, 0.f);   // max_k relu(x_k) == relu(max_k x_k)
  __shared__ float mv[128];
  mv[o] = m;
  __syncthreads();
  if (o<3){
    float acc = ldin(fc_b, o, f32);
    for(int c=0;c<128;c++) acc = fmaf(ldin(fc_w, (size_t)o*128+c, f32), mv[c], acc);
    size_t oi = ((size_t)b*3 + o)*NS + s;
    if (f32) ((float*)outv)[oi] = acc;
    else     ((unsigned short*)outv)[oi] = f2bf(acc);
  }
}

// ---------------------------------------------------------------------------
extern "C" void kernel_launch(void* const* d_in, const int* in_sizes, int n_in,
                              void* d_out, int out_size, void* d_ws, size_t ws_size,
                              hipStream_t stream){
  const void* pc1   = d_in[0];
  const void* feats = d_in[1];
  const void* W1    = d_in[2];
  const void* W2    = d_in[4];
  const void* W3    = d_in[6];
  const void* fcw   = d_in[8];
  const void* fcb   = d_in[9];
  char* ws = (char*)d_ws;
  int*      fps  = (int*)     (ws + 0);          // 32768 B
  float*    nxyz = (float*)   (ws + 32768);      // 98304 B
  int*      knn  = (int*)     (ws + 131072);     // 1048576 B
  float*    s1   = (float*)   (ws + 1179648);    // 4096 B
  float*    s2   = (float*)   (ws + 1183744);    // 4096 B
  float*    mub  = (float*)   (ws + 1187840);    // 12288 B
  float*    rsb  = (float*)   (ws + 1200128);    // 12288 B
  _Float16* Ha   = (_Float16*)(ws + 1212416);    // 67108864 B
  _Float16* Hb   = (_Float16*)(ws + 68321280);   // 67108864 B (total 135430144)
  _Float16* G    = Hb;  // G (8.9 MB) aliases Hb: read only by conv1, Hb first written by conv2

  feat_transpose<<<NB*64, 256, 0, stream>>>(feats, pc1, G);
  fps_kernel<<<NB, 512, 0, stream>>>(pc1, fps);
  knn_kernel<<<NB*NS, 256, 0, stream>>>(pc1, fps, nxyz, knn);

  hipMemsetAsync(s1, 0, 8192, stream);  // zeros s1+s2 (contiguous)
  conv_mfma<1><<<NM/128, 256, 0, stream>>>(pc1, G, knn, nxyz,
      (const _Float16*)nullptr, (const float*)nullptr, (const float*)nullptr, W1, Ha, s1, s2);
  stats_finalize<<<4,256,0,stream>>>(s1, s2, mub, rsb);

  hipMemsetAsync(s1, 0, 8192, stream);
  conv_mfma<2><<<NM/128, 256, 0, stream>>>(pc1, G, knn, nxyz,
      Ha, mub, rsb, W2, Hb, s1, s2);
  stats_finalize<<<4,256,0,stream>>>(s1, s2, mub+1024, rsb+1024);

  hipMemsetAsync(s1, 0, 8192, stream);
  conv_mfma<3><<<NM/128, 256, 0, stream>>>(pc1, G, knn, nxyz,
      Hb, mub+1024, rsb+1024, W3, Ha, s1, s2);
  stats_finalize<<<4,256,0,stream>>>(s1, s2, mub+2048, rsb+2048);

  final_kernel<<<NB*NS, 128, 0, stream>>>(pc1, Ha, mub+2048, rsb+2048, fcw, fcb, d_out);
}

// Round 5
// 1371.697 us; speedup vs baseline: 1.7435x; 1.0562x over previous
//
#include <hip/hip_runtime.h>
#include <hip/hip_fp16.h>

#define NB 8
#define NPTS 4096
#define NS 1024
#define NK 32
#define NM (NB*NS*NK)   // 262144 grouped points

typedef _Float16 f16x8 __attribute__((ext_vector_type(8)));
typedef float    f32x4 __attribute__((ext_vector_type(4)));
typedef float    f32x2 __attribute__((ext_vector_type(2)));

__device__ __forceinline__ float bf2f(unsigned short u){ return __uint_as_float(((unsigned)u)<<16); }
__device__ __forceinline__ unsigned short f2bf(float f){
  unsigned u = __float_as_uint(f);
  u = u + 0x7fffu + ((u>>16)&1u);   // RNE
  return (unsigned short)(u>>16);
}
__device__ __forceinline__ unsigned long long umax64(unsigned long long a, unsigned long long b){ return a>b?a:b; }
__device__ __forceinline__ unsigned long long umin64(unsigned long long a, unsigned long long b){ return a<b?a:b; }
__device__ __forceinline__ unsigned umin3u(unsigned a, unsigned b, unsigned c){
  unsigned m = a<b?a:b; return m<c?m:c;   // -> v_min3_u32
}

// ---- DPP wave64 reduce: row_shr 1/2/4/8 + row_bcast 15/31, result in lane 63.
#define DPP_STEP_MAX(x, ctrl, rm) { \
  unsigned _t = (unsigned)__builtin_amdgcn_update_dpp((int)(x), (int)(x), (ctrl), (rm), 0xf, false); \
  (x) = ((x) > _t) ? (x) : _t; }
#define DPP_STEP_MIN(x, ctrl, rm) { \
  unsigned _t = (unsigned)__builtin_amdgcn_update_dpp((int)(x), (int)(x), (ctrl), (rm), 0xf, false); \
  (x) = ((x) < _t) ? (x) : _t; }

__device__ __forceinline__ unsigned wave_max_u32(unsigned x){
  DPP_STEP_MAX(x, 0x111, 0xf);
  DPP_STEP_MAX(x, 0x112, 0xf);
  DPP_STEP_MAX(x, 0x114, 0xf);
  DPP_STEP_MAX(x, 0x118, 0xf);
  DPP_STEP_MAX(x, 0x142, 0xa);
  DPP_STEP_MAX(x, 0x143, 0xc);
  return (unsigned)__builtin_amdgcn_readlane((int)x, 63);
}
__device__ __forceinline__ unsigned wave_min_u32(unsigned x){
  DPP_STEP_MIN(x, 0x111, 0xf);
  DPP_STEP_MIN(x, 0x112, 0xf);
  DPP_STEP_MIN(x, 0x114, 0xf);
  DPP_STEP_MIN(x, 0x118, 0xf);
  DPP_STEP_MIN(x, 0x142, 0xa);
  DPP_STEP_MIN(x, 0x143, 0xc);
  return (unsigned)__builtin_amdgcn_readlane((int)x, 63);
}

// Runtime dtype detection (block-uniform scalar branch): f32 data read as bf16
// halves decodes huge/denormal or exact-zero; true bf16 N(0,1) does not.
__device__ __forceinline__ bool detect_f32(const unsigned short* __restrict__ u){
  int huge_=0, zero_=0;
  #pragma unroll
  for (int i=0;i<64;i++){
    unsigned short w = u[i];
    if ((w & 0x7fffu) == 0) { zero_++; continue; }
    float a = fabsf(bf2f(w));
    if (a > 1e6f || a < 1e-6f) huge_++;
  }
  return (huge_ >= 8) || (zero_ >= 24);
}
__device__ __forceinline__ float ldin(const void* p, size_t i, bool f32){
  if (f32) return ((const float*)p)[i];
  else     return bf2f(((const unsigned short*)p)[i]);
}

// ---------------------------------------------------------------------------
// FPS: one block/batch, 256 threads, 16 contiguous pts/thread as 8 f32x2
// packed pairs (v_pk_add/mul_f32, contract OFF -> exact RN, numpy order).
// Per iter: cp4[far] b128 read -> packed update -> v_max3 tree -> DPP max ->
// ballot/ctz/readlane -> 1 barrier -> 4-key u64 scan. Key dist<<32|(4095-n):
// max -> largest dist, tie -> lowest n (np.argmax first-max).
// ---------------------------------------------------------------------------
__global__ __launch_bounds__(256) void fps_kernel(const void* __restrict__ pc1,
                                                  int* __restrict__ fps_out){
  __shared__ __align__(16) float4 cp4[NPTS];
  __shared__ __align__(16) unsigned long long part[2][4];
  int b = blockIdx.x, t = threadIdx.x;
  const bool f32 = detect_f32((const unsigned short*)pc1);
  const size_t base = (size_t)b*3*NPTS;
  for (int i=t;i<NPTS;i+=256){
    float4 v;
    v.x = ldin(pc1, base+i, f32);
    v.y = ldin(pc1, base+NPTS+i, f32);
    v.z = ldin(pc1, base+2*NPTS+i, f32);
    v.w = 0.f;
    cp4[i] = v;
  }
  __syncthreads();
  f32x2 px[8],py[8],pz[8],dist[8];
  #pragma unroll
  for (int j=0;j<8;j++){
    float4 a = cp4[t*16+2*j], c = cp4[t*16+2*j+1];
    px[j] = f32x2{a.x, c.x};
    py[j] = f32x2{a.y, c.y};
    pz[j] = f32x2{a.z, c.z};
    dist[j] = f32x2{1e10f, 1e10f};
  }
  int far = 0;
  int w = t>>6, lane = t&63;
  for (int it=0; it<NS; it++){
    if (t==0) fps_out[b*NS+it] = far;
    float4 cc = cp4[far];
    f32x2 vcx = f32x2{cc.x,cc.x}, vcy = f32x2{cc.y,cc.y}, vcz = f32x2{cc.z,cc.z};
    {
      #pragma clang fp contract(off)
      #pragma unroll
      for (int j=0;j<8;j++){
        f32x2 dx = px[j]-vcx, dy = py[j]-vcy, dz = pz[j]-vcz;
        f32x2 d  = (dx*dx + dy*dy) + dz*dz;     // exact RN order: ((x2+y2)+z2)
        dist[j]  = __builtin_elementwise_min(dist[j], d);
      }
    }
    float d_[16];
    #pragma unroll
    for (int j=0;j<8;j++){ d_[2*j]=dist[j][0]; d_[2*j+1]=dist[j][1]; }
    float a0 = fmaxf(fmaxf(d_[0],d_[1]),d_[2]);      // -> v_max3_f32
    float a1 = fmaxf(fmaxf(d_[3],d_[4]),d_[5]);
    float a2 = fmaxf(fmaxf(d_[6],d_[7]),d_[8]);
    float a3 = fmaxf(fmaxf(d_[9],d_[10]),d_[11]);
    float a4 = fmaxf(fmaxf(d_[12],d_[13]),d_[14]);
    float b0 = fmaxf(fmaxf(a0,a1),a2);
    float b1 = fmaxf(fmaxf(a3,a4),d_[15]);
    float bl = fmaxf(b0,b1);
    int li = 0;
    #pragma unroll
    for (int i=15;i>=0;i--) if (d_[i]==bl) li = i;   // descending: final = lowest i
    unsigned blu = __float_as_uint(bl);               // dist>=0: bits monotone
    unsigned wm = wave_max_u32(blu);
    unsigned long long mk = __ballot(blu == wm);
    int l = __builtin_ctzll(mk);                      // lowest lane = lowest n
    int idx = __builtin_amdgcn_readlane(t*16+li, l);
    if (lane==0) part[it&1][w] = ((unsigned long long)wm<<32) | (unsigned)(NPTS-1-idx);
    __syncthreads();
    const ulonglong2* pp = (const ulonglong2*)&part[it&1][0];
    ulonglong2 A = pp[0], B = pp[1];
    unsigned long long m = umax64(umax64(A.x,A.y), umax64(B.x,B.y));
    far = NPTS-1 - (int)(m & 0xffffffffu);
  }
}

// ---------------------------------------------------------------------------
// kNN: one block per (b,s), 256 threads, 16 contiguous pts/thread as u32
// ordered-dist regs. 32 rounds: v_min3_u32 tree + post-scan first-idx + DPP
// min + ballot + 1 barrier + 4-key u64 scan; winner masked via cndmask.
// ---------------------------------------------------------------------------
__global__ __launch_bounds__(256) void knn_kernel(const void* __restrict__ pc1,
                                                  const int* __restrict__ fps_idx,
                                                  float* __restrict__ new_xyz,
                                                  int* __restrict__ knn_idx){
  __shared__ __align__(16) float xs[NPTS], ys[NPTS], zs[NPTS];
  __shared__ __align__(16) unsigned long long part[2][4];
  int blk = blockIdx.x;
  int b = blk >> 10;
  int t = threadIdx.x;
  const bool f32 = detect_f32((const unsigned short*)pc1);
  if (f32){
    const float* base = (const float*)pc1 + (size_t)b*3*NPTS;
    for (int i=t;i<NPTS;i+=256){ xs[i]=base[i]; ys[i]=base[NPTS+i]; zs[i]=base[2*NPTS+i]; }
  } else {
    const unsigned short* base = (const unsigned short*)pc1 + (size_t)b*3*NPTS;
    for (int i=t;i<NPTS;i+=256){ xs[i]=bf2f(base[i]); ys[i]=bf2f(base[NPTS+i]); zs[i]=bf2f(base[2*NPTS+i]); }
  }
  __syncthreads();
  int n0 = fps_idx[blk];
  float qx=xs[n0], qy=ys[n0], qz=zs[n0];
  if (t==0){ new_xyz[(size_t)blk*3]=qx; new_xyz[(size_t)blk*3+1]=qy; new_xyz[(size_t)blk*3+2]=qz; }
  float qn = __fadd_rn(__fadd_rn(__fmul_rn(qx,qx),__fmul_rn(qy,qy)),__fmul_rn(qz,qz));
  unsigned db[16];
  #pragma unroll
  for(int i=0;i<16;i++){
    int n = t*16 + i;                            // contiguous chunk per thread
    float x=xs[n], y=ys[n], z=zs[n];
    float pn = __fadd_rn(__fadd_rn(__fmul_rn(x,x),__fmul_rn(y,y)),__fmul_rn(z,z));
    float dt = __fadd_rn(__fadd_rn(__fmul_rn(qx,x),__fmul_rn(qy,y)),__fmul_rn(qz,z));
    float d  = __fsub_rn(__fadd_rn(qn,pn), __fmul_rn(2.f,dt));
    unsigned u = __float_as_uint(d);
    db[i] = (u & 0x80000000u) ? ~u : (u | 0x80000000u);  // order-preserving map
  }
  int w = t>>6, lane = t&63;
  for (int r=0;r<NK;r++){
    unsigned a0 = umin3u(db[0],db[1],db[2]);
    unsigned a1 = umin3u(db[3],db[4],db[5]);
    unsigned a2 = umin3u(db[6],db[7],db[8]);
    unsigned a3 = umin3u(db[9],db[10],db[11]);
    unsigned a4 = umin3u(db[12],db[13],db[14]);
    unsigned b0 = umin3u(a0,a1,a2);
    unsigned b1 = umin3u(a3,a4,db[15]);
    unsigned bl = b0<b1 ? b0 : b1;
    int li = 0;
    #pragma unroll
    for (int i=15;i>=0;i--) if (db[i]==bl) li = i;
    unsigned wm = wave_min_u32(bl);
    unsigned long long mk = __ballot(bl == wm);
    int l = __builtin_ctzll(mk);
    int idx = __builtin_amdgcn_readlane(t*16+li, l);
    if (lane==0) part[r&1][w] = ((unsigned long long)wm<<32) | (unsigned)idx;
    __syncthreads();
    const ulonglong2* pp = (const ulonglong2*)&part[r&1][0];
    ulonglong2 A=pp[0], B=pp[1];
    unsigned long long m = umin64(umin64(A.x,A.y), umin64(B.x,B.y));
    int n = (int)(m & 0xffffffffu);
    if (t==0) knn_idx[(size_t)blk*NK + r] = n;
    bool mine = ((n>>4) == t);
    #pragma unroll
    for (int i=0;i<16;i++)
      if (mine && ((n&15)==i)) db[i] = 0xFFFFFFFFu;
  }
}

// ---------------------------------------------------------------------------
// feats [B,128,N] (f32/bf16) -> G [B,N,136] fp16; block 0 also zeroes the six
// stat buffers (6144 f32) so no memset nodes are needed (ws is 0xAA-poisoned).
// ---------------------------------------------------------------------------
__global__ __launch_bounds__(256) void feat_transpose(const void* __restrict__ feats,
                                                      const void* __restrict__ pc1,
                                                      _Float16* __restrict__ G,
                                                      float* __restrict__ statz){
  __shared__ float tile[128][65];
  const bool f32 = detect_f32((const unsigned short*)pc1);
  int blk = blockIdx.x;             // b*64 + ntile
  int b = blk>>6, n0 = (blk&63)*64;
  int t = threadIdx.x;
  if (blk==0){
    for (int i=t;i<6144;i+=256) statz[i]=0.f;
  }
  #pragma unroll 4
  for (int i=0;i<32;i++){
    int idx = i*256 + t;
    int c = idx>>6, n = idx&63;
    tile[c][n] = ldin(feats, ((size_t)b*128 + c)*NPTS + n0 + n, f32);
  }
  __syncthreads();
  #pragma unroll 4
  for (int i=0;i<32;i++){
    int idx = i*256 + t;
    int n = idx>>7, c = idx&127;
    G[((size_t)b*NPTS + n0 + n)*136 + 3 + c] = (_Float16)tile[c][n];
  }
  if (t<64){
    size_t gb = ((size_t)b*NPTS + n0 + t)*136;
    G[gb]=(_Float16)0.f; G[gb+1]=(_Float16)0.f; G[gb+2]=(_Float16)0.f;
    #pragma unroll
    for (int c=131;c<136;c++) G[gb+c]=(_Float16)0.f;
  }
}

// ---------------------------------------------------------------------------
// MFMA conv: block = 128 pts x 128 outs, 4 waves at 64x64, K chunks of 32.
// mfma_f32_16x16x32_f16, f32 accumulate. LAYER 1: A from G (knn gather)+dxyz,
// K 131->160. LAYER 2/3: mu/rs computed inline from prev-layer sums, then
// A = relu((Hin-mu)*rs). Stats -> per-(b,o) f32 atomics. Biases cancel.
// ---------------------------------------------------------------------------
template<int LAYER>
__global__ __launch_bounds__(256) void conv_mfma(
    const void* __restrict__ pc1,
    const _Float16* __restrict__ G,
    const int* __restrict__ knn_idx,
    const float* __restrict__ new_xyz,
    const _Float16* __restrict__ Hin,
    const float* __restrict__ gp1,
    const float* __restrict__ gp2,
    const void* __restrict__ W,
    _Float16* __restrict__ Hout,
    float* __restrict__ gs1, float* __restrict__ gs2)
{
  constexpr int KC  = (LAYER==1)?131:128;
  constexpr int KCP = (LAYER==1)?160:128;
  constexpr int HSW = (LAYER==1)?168:136;
  __shared__ __align__(16) _Float16 hs[128][HSW];
  __shared__ __align__(16) _Float16 wt[128][40];
  __shared__ float red1[4][64], red2[4][64];
  __shared__ int   nidx[128];
  __shared__ float cxyz[4][3];
  __shared__ float smu[128], srs[128];
  int blk = blockIdx.x;
  int m0 = blk*128;
  int b  = m0 >> 15;
  int t  = threadIdx.x;
  const bool f32 = detect_f32((const unsigned short*)pc1);
  int w = t>>6, lane = t&63;
  int l16 = lane&15, q = lane>>4, q8 = q*8;
  int wr = (w&1)*64, wc = (w>>1)*64;

  if (LAYER==1){
    if (t<128) nidx[t] = knn_idx[m0+t];
    if (t<12)  cxyz[t/3][t%3] = new_xyz[(size_t)(m0>>5)*3 + t];
    __syncthreads();
    for (int u=t; u<128*17; u+=256){
      int p = u/17, qq = u - p*17;
      const f16x8* src = (const f16x8*)(G + ((size_t)b*NPTS + nidx[p])*136 + qq*8);
      *(f16x8*)&hs[p][qq*8] = *src;
    }
    for (int u=t; u<128*3; u+=256){
      int p = u/3, qq = u - p*3;
      uint4 z; z.x=z.y=z.z=z.w=0u;
      *(uint4*)&hs[p][136+qq*8] = z;
    }
    __syncthreads();
    if (t<128){
      int n = nidx[t];
      float cx = cxyz[t>>5][0], cy = cxyz[t>>5][1], cz = cxyz[t>>5][2];
      hs[t][0] = (_Float16)(ldin(pc1, ((size_t)b*3+0)*NPTS+n, f32) - cx);
      hs[t][1] = (_Float16)(ldin(pc1, ((size_t)b*3+1)*NPTS+n, f32) - cy);
      hs[t][2] = (_Float16)(ldin(pc1, ((size_t)b*3+2)*NPTS+n, f32) - cz);
    }
    __syncthreads();
  } else {
    if (t<128){
      const float inv = 1.0f/32768.0f;
      float m = gp1[b*128+t]*inv;
      smu[t] = m;
      srs[t] = rsqrtf(gp2[b*128+t]*inv - m*m + 1e-5f);
    }
    __syncthreads();
    int p = t & 127, hi = t>>7;
    const _Float16* src = Hin + (size_t)(m0+p)*128 + hi*64;
    #pragma unroll
    for (int j=0;j<8;j++){
      f16x8 v = *(const f16x8*)(src + j*8);
      f16x8 o;
      #pragma unroll
      for (int e=0;e<8;e++){
        int c = hi*64 + j*8 + e;
        float x = ((float)v[e] - smu[c]) * srs[c];
        o[e] = (_Float16)(x > 0.f ? x : 0.f);
      }
      *(f16x8*)&hs[p][hi*64 + j*8] = o;
    }
    __syncthreads();
  }

  f32x4 acc[4][4];
  #pragma unroll
  for (int i=0;i<4;i++)
    #pragma unroll
    for (int c=0;c<4;c++){ acc[i][c][0]=0.f; acc[i][c][1]=0.f; acc[i][c][2]=0.f; acc[i][c][3]=0.f; }

  for (int k0=0; k0<KCP; k0+=32){
    {
      int o = t>>1, half = t&1;
      f16x8 w0, w1;
      #pragma unroll
      for (int jj=0;jj<8;jj++){
        int c0 = k0 + half*16 + jj, c1 = c0 + 8;
        w0[jj] = (_Float16)((c0<KC) ? ldin(W, (size_t)o*KC + c0, f32) : 0.f);
        w1[jj] = (_Float16)((c1<KC) ? ldin(W, (size_t)o*KC + c1, f32) : 0.f);
      }
      *(f16x8*)&wt[o][half*16]     = w0;
      *(f16x8*)&wt[o][half*16 + 8] = w1;
    }
    __syncthreads();
    f16x8 av[4], bv[4];
    #pragma unroll
    for (int i=0;i<4;i++) av[i] = *(const f16x8*)&hs[wr + i*16 + l16][k0 + q8];
    #pragma unroll
    for (int c=0;c<4;c++) bv[c] = *(const f16x8*)&wt[wc + c*16 + l16][q8];
    #pragma unroll
    for (int i=0;i<4;i++)
      #pragma unroll
      for (int c=0;c<4;c++)
        acc[i][c] = __builtin_amdgcn_mfma_f32_16x16x32_f16(av[i], bv[c], acc[i][c], 0,0,0);
    __syncthreads();
  }

  #pragma unroll
  for (int c=0;c<4;c++){
    int o = wc + c*16 + l16;
    float s1=0.f, s2=0.f;
    #pragma unroll
    for (int i=0;i<4;i++){
      int row = wr + i*16 + q*4;
      #pragma unroll
      for (int r=0;r<4;r++){
        float v = acc[i][c][r];
        Hout[(size_t)(m0 + row + r)*128 + o] = (_Float16)v;
        s1 += v; s2 = fmaf(v,v,s2);
      }
    }
    s1 += __shfl_xor(s1, 16, 64); s1 += __shfl_xor(s1, 32, 64);
    s2 += __shfl_xor(s2, 16, 64); s2 += __shfl_xor(s2, 32, 64);
    if (q==0){ red1[w][c*16+l16] = s1; red2[w][c*16+l16] = s2; }
  }
  __syncthreads();
  if (t<128){
    int lo = t & 63, g = (t>>6)*2;
    unsafeAtomicAdd(&gs1[b*128+t], red1[g][lo] + red1[g+1][lo]);
    unsafeAtomicAdd(&gs2[b*128+t], red2[g][lo] + red2[g+1][lo]);
  }
}

// ---------------------------------------------------------------------------
// Final: per (b,s): mu/rs from layer-3 sums, norm+relu, max over K, fc 128->3
// ---------------------------------------------------------------------------
__global__ __launch_bounds__(128) void final_kernel(
    const void* __restrict__ pc1,
    const _Float16* __restrict__ H,
    const float* __restrict__ gp1, const float* __restrict__ gp2,
    const void* __restrict__ fc_w, const void* __restrict__ fc_b,
    void* __restrict__ outv)
{
  int blk = blockIdx.x;       // b*1024+s
  int b = blk>>10, s = blk & 1023;
  int o = threadIdx.x;
  const bool f32 = detect_f32((const unsigned short*)pc1);
  int bo = b*128 + o;
  const float inv = 1.0f/32768.0f;
  float mu_ = gp1[bo]*inv;
  float rs_ = rsqrtf(gp2[bo]*inv - mu_*mu_ + 1e-5f);
  const _Float16* hp = H + (size_t)blk*NK*128 + o;
  float m = -1e30f;
  #pragma unroll 4
  for(int k=0;k<NK;k++){
    float v = ((float)hp[(size_t)k*128] - mu_)*rs_;
    m = fmaxf(m, v);
  }
  m = fmaxf(m, 0.f);
  __shared__ float mv[128];
  mv[o] = m;
  __syncthreads();
  if (o<3){
    float acc = ldin(fc_b, o, f32);
    for(int c=0;c<128;c++) acc = fmaf(ldin(fc_w, (size_t)o*128+c, f32), mv[c], acc);
    size_t oi = ((size_t)b*3 + o)*NS + s;
    if (f32) ((float*)outv)[oi] = acc;
    else     ((unsigned short*)outv)[oi] = f2bf(acc);
  }
}

// ---------------------------------------------------------------------------
extern "C" void kernel_launch(void* const* d_in, const int* in_sizes, int n_in,
                              void* d_out, int out_size, void* d_ws, size_t ws_size,
                              hipStream_t stream){
  const void* pc1   = d_in[0];
  const void* feats = d_in[1];
  const void* W1    = d_in[2];
  const void* W2    = d_in[4];
  const void* W3    = d_in[6];
  const void* fcw   = d_in[8];
  const void* fcb   = d_in[9];
  char* ws = (char*)d_ws;
  int*      fps  = (int*)     (ws + 0);          // 32768 B
  float*    nxyz = (float*)   (ws + 32768);      // 98304 B
  int*      knn  = (int*)     (ws + 131072);     // 1048576 B
  float*    st   = (float*)   (ws + 1179648);    // 6*1024*4 = 24576 B  [s1a s2a s1b s2b s1c s2c]
  _Float16* Ha   = (_Float16*)(ws + 1204224);    // 67108864 B
  _Float16* Hb   = (_Float16*)(ws + 68313088);   // 67108864 B (total 135421952)
  _Float16* G    = Hb;  // G (8.9 MB) aliases Hb: read only by conv1, Hb first written by conv2

  feat_transpose<<<NB*64, 256, 0, stream>>>(feats, pc1, G, st);
  fps_kernel<<<NB, 256, 0, stream>>>(pc1, fps);
  knn_kernel<<<NB*NS, 256, 0, stream>>>(pc1, fps, nxyz, knn);

  conv_mfma<1><<<NM/128, 256, 0, stream>>>(pc1, G, knn, nxyz,
      (const _Float16*)nullptr, (const float*)nullptr, (const float*)nullptr,
      W1, Ha, st, st+1024);
  conv_mfma<2><<<NM/128, 256, 0, stream>>>(pc1, G, knn, nxyz,
      Ha, st, st+1024, W2, Hb, st+2048, st+3072);
  conv_mfma<3><<<NM/128, 256, 0, stream>>>(pc1, G, knn, nxyz,
      Hb, st+2048, st+3072, W3, Ha, st+4096, st+5120);

  final_kernel<<<NB*NS, 128, 0, stream>>>(pc1, Ha, st+4096, st+5120, fcw, fcb, d_out);
}

// Round 6
// 1333.517 us; speedup vs baseline: 1.7934x; 1.0286x over previous
//
#include <hip/hip_runtime.h>
#include <hip/hip_fp16.h>

#define NB 8
#define NPTS 4096
#define NS 1024
#define NK 32
#define NM (NB*NS*NK)   // 262144 grouped points

typedef _Float16 f16x8 __attribute__((ext_vector_type(8)));
typedef float    f32x4 __attribute__((ext_vector_type(4)));
typedef float    f32x2 __attribute__((ext_vector_type(2)));

__device__ __forceinline__ float bf2f(unsigned short u){ return __uint_as_float(((unsigned)u)<<16); }
__device__ __forceinline__ unsigned short f2bf(float f){
  unsigned u = __float_as_uint(f);
  u = u + 0x7fffu + ((u>>16)&1u);   // RNE
  return (unsigned short)(u>>16);
}
__device__ __forceinline__ unsigned long long umax64(unsigned long long a, unsigned long long b){ return a>b?a:b; }
__device__ __forceinline__ unsigned long long umin64(unsigned long long a, unsigned long long b){ return a<b?a:b; }
__device__ __forceinline__ unsigned umin3u(unsigned a, unsigned b, unsigned c){
  unsigned m = a<b?a:b; return m<c?m:c;   // -> v_min3_u32
}

// ---- DPP wave64 reduce: row_shr 1/2/4/8 + row_bcast 15/31, result in lane 63.
#define DPP_STEP_MAX(x, ctrl, rm) { \
  unsigned _t = (unsigned)__builtin_amdgcn_update_dpp((int)(x), (int)(x), (ctrl), (rm), 0xf, false); \
  (x) = ((x) > _t) ? (x) : _t; }
#define DPP_STEP_MIN(x, ctrl, rm) { \
  unsigned _t = (unsigned)__builtin_amdgcn_update_dpp((int)(x), (int)(x), (ctrl), (rm), 0xf, false); \
  (x) = ((x) < _t) ? (x) : _t; }

__device__ __forceinline__ unsigned wave_max_u32(unsigned x){
  DPP_STEP_MAX(x, 0x111, 0xf);
  DPP_STEP_MAX(x, 0x112, 0xf);
  DPP_STEP_MAX(x, 0x114, 0xf);
  DPP_STEP_MAX(x, 0x118, 0xf);
  DPP_STEP_MAX(x, 0x142, 0xa);
  DPP_STEP_MAX(x, 0x143, 0xc);
  return (unsigned)__builtin_amdgcn_readlane((int)x, 63);
}
__device__ __forceinline__ unsigned wave_min_u32(unsigned x){
  DPP_STEP_MIN(x, 0x111, 0xf);
  DPP_STEP_MIN(x, 0x112, 0xf);
  DPP_STEP_MIN(x, 0x114, 0xf);
  DPP_STEP_MIN(x, 0x118, 0xf);
  DPP_STEP_MIN(x, 0x142, 0xa);
  DPP_STEP_MIN(x, 0x143, 0xc);
  return (unsigned)__builtin_amdgcn_readlane((int)x, 63);
}

// Runtime dtype detection (block-uniform scalar branch): f32 data read as bf16
// halves decodes huge/denormal or exact-zero; true bf16 N(0,1) does not.
__device__ __forceinline__ bool detect_f32(const unsigned short* __restrict__ u){
  int huge_=0, zero_=0;
  #pragma unroll
  for (int i=0;i<64;i++){
    unsigned short w = u[i];
    if ((w & 0x7fffu) == 0) { zero_++; continue; }
    float a = fabsf(bf2f(w));
    if (a > 1e6f || a < 1e-6f) huge_++;
  }
  return (huge_ >= 8) || (zero_ >= 24);
}
__device__ __forceinline__ float ldin(const void* p, size_t i, bool f32){
  if (f32) return ((const float*)p)[i];
  else     return bf2f(((const unsigned short*)p)[i]);
}

// ---------------------------------------------------------------------------
// FPS: unchanged from round 5 (544 us; latency-bound serial chain).
// ---------------------------------------------------------------------------
__global__ __launch_bounds__(256) void fps_kernel(const void* __restrict__ pc1,
                                                  int* __restrict__ fps_out){
  __shared__ __align__(16) float4 cp4[NPTS];
  __shared__ __align__(16) unsigned long long part[2][4];
  int b = blockIdx.x, t = threadIdx.x;
  const bool f32 = detect_f32((const unsigned short*)pc1);
  const size_t base = (size_t)b*3*NPTS;
  for (int i=t;i<NPTS;i+=256){
    float4 v;
    v.x = ldin(pc1, base+i, f32);
    v.y = ldin(pc1, base+NPTS+i, f32);
    v.z = ldin(pc1, base+2*NPTS+i, f32);
    v.w = 0.f;
    cp4[i] = v;
  }
  __syncthreads();
  f32x2 px[8],py[8],pz[8],dist[8];
  #pragma unroll
  for (int j=0;j<8;j++){
    float4 a = cp4[t*16+2*j], c = cp4[t*16+2*j+1];
    px[j] = f32x2{a.x, c.x};
    py[j] = f32x2{a.y, c.y};
    pz[j] = f32x2{a.z, c.z};
    dist[j] = f32x2{1e10f, 1e10f};
  }
  int far = 0;
  int w = t>>6, lane = t&63;
  for (int it=0; it<NS; it++){
    if (t==0) fps_out[b*NS+it] = far;
    float4 cc = cp4[far];
    f32x2 vcx = f32x2{cc.x,cc.x}, vcy = f32x2{cc.y,cc.y}, vcz = f32x2{cc.z,cc.z};
    {
      #pragma clang fp contract(off)
      #pragma unroll
      for (int j=0;j<8;j++){
        f32x2 dx = px[j]-vcx, dy = py[j]-vcy, dz = pz[j]-vcz;
        f32x2 d  = (dx*dx + dy*dy) + dz*dz;     // exact RN order: ((x2+y2)+z2)
        dist[j]  = __builtin_elementwise_min(dist[j], d);
      }
    }
    float d_[16];
    #pragma unroll
    for (int j=0;j<8;j++){ d_[2*j]=dist[j][0]; d_[2*j+1]=dist[j][1]; }
    float a0 = fmaxf(fmaxf(d_[0],d_[1]),d_[2]);      // -> v_max3_f32
    float a1 = fmaxf(fmaxf(d_[3],d_[4]),d_[5]);
    float a2 = fmaxf(fmaxf(d_[6],d_[7]),d_[8]);
    float a3 = fmaxf(fmaxf(d_[9],d_[10]),d_[11]);
    float a4 = fmaxf(fmaxf(d_[12],d_[13]),d_[14]);
    float b0 = fmaxf(fmaxf(a0,a1),a2);
    float b1 = fmaxf(fmaxf(a3,a4),d_[15]);
    float bl = fmaxf(b0,b1);
    int li = 0;
    #pragma unroll
    for (int i=15;i>=0;i--) if (d_[i]==bl) li = i;   // descending: final = lowest i
    unsigned blu = __float_as_uint(bl);               // dist>=0: bits monotone
    unsigned wm = wave_max_u32(blu);
    unsigned long long mk = __ballot(blu == wm);
    int l = __builtin_ctzll(mk);                      // lowest lane = lowest n
    int idx = __builtin_amdgcn_readlane(t*16+li, l);
    if (lane==0) part[it&1][w] = ((unsigned long long)wm<<32) | (unsigned)(NPTS-1-idx);
    __syncthreads();
    const ulonglong2* pp = (const ulonglong2*)&part[it&1][0];
    ulonglong2 A = pp[0], B = pp[1];
    unsigned long long m = umax64(umax64(A.x,A.y), umax64(B.x,B.y));
    far = NPTS-1 - (int)(m & 0xffffffffu);
  }
}

// ---------------------------------------------------------------------------
// kNN v2: one block per (b,s), 256 thr. Each wave autonomously extracts the
// top-32 of its 1024 pts (16/lane, dists in LDS, 4 group-minima cached in
// regs) with ZERO barriers: per round = min3 tree over 4 + DPP min + ballot/
// ctz/readlane; winner lane patches its group (speculative b128 reload hides
// under the DPP chain). Then one barrier + exact rank-merge of the 4 sorted
// 32-lists of unique (dist,idx) u64 keys via binary search; rank<32 scatters.
// Set AND order match lax.top_k(-d) exactly (keys globally unique).
// ---------------------------------------------------------------------------
__global__ __launch_bounds__(256) void knn_kernel(const void* __restrict__ pc1,
                                                  const int* __restrict__ fps_idx,
                                                  float* __restrict__ new_xyz,
                                                  int* __restrict__ knn_idx){
  __shared__ __align__(16) float xs[NPTS], ys[NPTS], zs[NPTS];   // 48 KB
  __shared__ __align__(16) unsigned dbs[256*20];                 // 20 KB, stride 20 (conflict-free b128)
  __shared__ __align__(16) unsigned long long lists[4][NK];      // 1 KB
  int blk = blockIdx.x;   // b*1024 + s
  int b = blk >> 10;
  int t = threadIdx.x;
  int w = t>>6, lane = t&63;
  const bool f32 = detect_f32((const unsigned short*)pc1);
  if (f32){
    const float* base = (const float*)pc1 + (size_t)b*3*NPTS;
    for (int i=t;i<NPTS;i+=256){ xs[i]=base[i]; ys[i]=base[NPTS+i]; zs[i]=base[2*NPTS+i]; }
  } else {
    const unsigned short* base = (const unsigned short*)pc1 + (size_t)b*3*NPTS;
    for (int i=t;i<NPTS;i+=256){ xs[i]=bf2f(base[i]); ys[i]=bf2f(base[NPTS+i]); zs[i]=bf2f(base[2*NPTS+i]); }
  }
  __syncthreads();
  int n0 = fps_idx[blk];
  float qx=xs[n0], qy=ys[n0], qz=zs[n0];
  if (t==0){ new_xyz[(size_t)blk*3]=qx; new_xyz[(size_t)blk*3+1]=qy; new_xyz[(size_t)blk*3+2]=qz; }
  float qn = __fadd_rn(__fadd_rn(__fmul_rn(qx,qx),__fmul_rn(qy,qy)),__fmul_rn(qz,qz));
  unsigned dv[16];
  #pragma unroll
  for (int i=0;i<16;i++){
    int n = t*16 + i;                            // contiguous chunk per thread
    float x=xs[n], y=ys[n], z=zs[n];
    float pn = __fadd_rn(__fadd_rn(__fmul_rn(x,x),__fmul_rn(y,y)),__fmul_rn(z,z));
    float dt = __fadd_rn(__fadd_rn(__fmul_rn(qx,x),__fmul_rn(qy,y)),__fmul_rn(qz,z));
    float d  = __fsub_rn(__fadd_rn(qn,pn), __fmul_rn(2.f,dt));
    unsigned u = __float_as_uint(d);
    dv[i] = (u & 0x80000000u) ? ~u : (u | 0x80000000u);  // order-preserving map
  }
  #pragma unroll
  for (int g=0; g<4; g++){
    uint4 v; v.x=dv[4*g]; v.y=dv[4*g+1]; v.z=dv[4*g+2]; v.w=dv[4*g+3];
    *(uint4*)&dbs[t*20 + 4*g] = v;               // own region: no barrier needed
  }
  unsigned gm[4]; int gj[4];
  #pragma unroll
  for (int g=0; g<4; g++){
    unsigned m = dv[4*g]; int j = 0;
    if (dv[4*g+1] < m){ m = dv[4*g+1]; j = 1; }  // strict <, ascending: first min
    if (dv[4*g+2] < m){ m = dv[4*g+2]; j = 2; }
    if (dv[4*g+3] < m){ m = dv[4*g+3]; j = 3; }
    gm[g] = m; gj[g] = j;
  }
  #pragma unroll 1
  for (int r=0; r<NK; r++){
    unsigned bl = umin3u(gm[0],gm[1],gm[2]);
    bl = bl < gm[3] ? bl : gm[3];
    int bg = 3;                                   // descending: final = lowest g
    if (gm[2]==bl) bg=2;
    if (gm[1]==bl) bg=1;
    if (gm[0]==bl) bg=0;
    int lj = gj[0];
    if (bg==1) lj=gj[1];
    if (bg==2) lj=gj[2];
    if (bg==3) lj=gj[3];
    int bn = (t<<4) + (bg<<2) + lj;               // global point idx
    // speculative reload of own best group; latency hides under DPP chain
    uint4 gv = *(const uint4*)&dbs[t*20 + (bg<<2)];
    unsigned wm = wave_min_u32(bl);
    unsigned long long mk = __ballot(bl == wm);
    int l = __builtin_ctzll(mk);                  // lowest lane = lowest idx on tie
    int idx = __builtin_amdgcn_readlane(bn, l);
    if (lane==0) lists[w][r] = ((unsigned long long)wm<<32) | (unsigned)idx;
    if (lane==l){
      unsigned g0 = (lj==0)?0xFFFFFFFFu:gv.x;
      unsigned g1 = (lj==1)?0xFFFFFFFFu:gv.y;
      unsigned g2 = (lj==2)?0xFFFFFFFFu:gv.z;
      unsigned g3 = (lj==3)?0xFFFFFFFFu:gv.w;
      uint4 nv; nv.x=g0; nv.y=g1; nv.z=g2; nv.w=g3;
      *(uint4*)&dbs[t*20 + (bg<<2)] = nv;
      unsigned m = g0; int j = 0;
      if (g1 < m){ m=g1; j=1; }
      if (g2 < m){ m=g2; j=2; }
      if (g3 < m){ m=g3; j=3; }
      if (bg==0){ gm[0]=m; gj[0]=j; }
      if (bg==1){ gm[1]=m; gj[1]=j; }
      if (bg==2){ gm[2]=m; gj[2]=j; }
      if (bg==3){ gm[3]=m; gj[3]=j; }
    }
  }
  __syncthreads();
  if (t < 128){
    int cl = t>>5, p = t&31;
    unsigned long long K = lists[cl][p];
    int rank = p;                                 // lists strictly increasing
    #pragma unroll
    for (int ol=0; ol<4; ol++){
      if (ol==cl) continue;
      int lo = 0;                                 // count of elems < K
      if (lists[ol][15]    < K) lo  = 16;
      if (lists[ol][lo+7]  < K) lo += 8;
      if (lists[ol][lo+3]  < K) lo += 4;
      if (lists[ol][lo+1]  < K) lo += 2;
      if (lists[ol][lo]    < K) lo += 1;
      rank += lo;
    }
    if (rank < NK) knn_idx[(size_t)blk*NK + rank] = (int)(K & 0xffffffffu);
  }
}

// ---------------------------------------------------------------------------
// feats [B,128,N] (f32/bf16) -> G [B,N,136] fp16; block 0 also zeroes the six
// stat buffers (6144 f32) so no memset nodes are needed (ws is 0xAA-poisoned).
// ---------------------------------------------------------------------------
__global__ __launch_bounds__(256) void feat_transpose(const void* __restrict__ feats,
                                                      const void* __restrict__ pc1,
                                                      _Float16* __restrict__ G,
                                                      float* __restrict__ statz){
  __shared__ float tile[128][65];
  const bool f32 = detect_f32((const unsigned short*)pc1);
  int blk = blockIdx.x;             // b*64 + ntile
  int b = blk>>6, n0 = (blk&63)*64;
  int t = threadIdx.x;
  if (blk==0){
    for (int i=t;i<6144;i+=256) statz[i]=0.f;
  }
  #pragma unroll 4
  for (int i=0;i<32;i++){
    int idx = i*256 + t;
    int c = idx>>6, n = idx&63;
    tile[c][n] = ldin(feats, ((size_t)b*128 + c)*NPTS + n0 + n, f32);
  }
  __syncthreads();
  #pragma unroll 4
  for (int i=0;i<32;i++){
    int idx = i*256 + t;
    int n = idx>>7, c = idx&127;
    G[((size_t)b*NPTS + n0 + n)*136 + 3 + c] = (_Float16)tile[c][n];
  }
  if (t<64){
    size_t gb = ((size_t)b*NPTS + n0 + t)*136;
    G[gb]=(_Float16)0.f; G[gb+1]=(_Float16)0.f; G[gb+2]=(_Float16)0.f;
    #pragma unroll
    for (int c=131;c<136;c++) G[gb+c]=(_Float16)0.f;
  }
}

// ---------------------------------------------------------------------------
// MFMA conv: block = 128 pts x 128 outs, 4 waves at 64x64, K chunks of 32.
// mfma_f32_16x16x32_f16, f32 accumulate. LAYER 1: A from G (knn gather)+dxyz,
// K 131->160. LAYER 2/3: mu/rs computed inline from prev-layer sums, then
// A = relu((Hin-mu)*rs). Stats -> per-(b,o) f32 atomics. Biases cancel.
// ---------------------------------------------------------------------------
template<int LAYER>
__global__ __launch_bounds__(256) void conv_mfma(
    const void* __restrict__ pc1,
    const _Float16* __restrict__ G,
    const int* __restrict__ knn_idx,
    const float* __restrict__ new_xyz,
    const _Float16* __restrict__ Hin,
    const float* __restrict__ gp1,
    const float* __restrict__ gp2,
    const void* __restrict__ W,
    _Float16* __restrict__ Hout,
    float* __restrict__ gs1, float* __restrict__ gs2)
{
  constexpr int KC  = (LAYER==1)?131:128;
  constexpr int KCP = (LAYER==1)?160:128;
  constexpr int HSW = (LAYER==1)?168:136;
  __shared__ __align__(16) _Float16 hs[128][HSW];
  __shared__ __align__(16) _Float16 wt[128][40];
  __shared__ float red1[4][64], red2[4][64];
  __shared__ int   nidx[128];
  __shared__ float cxyz[4][3];
  __shared__ float smu[128], srs[128];
  int blk = blockIdx.x;
  int m0 = blk*128;
  int b  = m0 >> 15;
  int t  = threadIdx.x;
  const bool f32 = detect_f32((const unsigned short*)pc1);
  int w = t>>6, lane = t&63;
  int l16 = lane&15, q = lane>>4, q8 = q*8;
  int wr = (w&1)*64, wc = (w>>1)*64;

  if (LAYER==1){
    if (t<128) nidx[t] = knn_idx[m0+t];
    if (t<12)  cxyz[t/3][t%3] = new_xyz[(size_t)(m0>>5)*3 + t];
    __syncthreads();
    for (int u=t; u<128*17; u+=256){
      int p = u/17, qq = u - p*17;
      const f16x8* src = (const f16x8*)(G + ((size_t)b*NPTS + nidx[p])*136 + qq*8);
      *(f16x8*)&hs[p][qq*8] = *src;
    }
    for (int u=t; u<128*3; u+=256){
      int p = u/3, qq = u - p*3;
      uint4 z; z.x=z.y=z.z=z.w=0u;
      *(uint4*)&hs[p][136+qq*8] = z;
    }
    __syncthreads();
    if (t<128){
      int n = nidx[t];
      float cx = cxyz[t>>5][0], cy = cxyz[t>>5][1], cz = cxyz[t>>5][2];
      hs[t][0] = (_Float16)(ldin(pc1, ((size_t)b*3+0)*NPTS+n, f32) - cx);
      hs[t][1] = (_Float16)(ldin(pc1, ((size_t)b*3+1)*NPTS+n, f32) - cy);
      hs[t][2] = (_Float16)(ldin(pc1, ((size_t)b*3+2)*NPTS+n, f32) - cz);
    }
    __syncthreads();
  } else {
    if (t<128){
      const float inv = 1.0f/32768.0f;
      float m = gp1[b*128+t]*inv;
      smu[t] = m;
      srs[t] = rsqrtf(gp2[b*128+t]*inv - m*m + 1e-5f);
    }
    __syncthreads();
    int p = t & 127, hi = t>>7;
    const _Float16* src = Hin + (size_t)(m0+p)*128 + hi*64;
    #pragma unroll
    for (int j=0;j<8;j++){
      f16x8 v = *(const f16x8*)(src + j*8);
      f16x8 o;
      #pragma unroll
      for (int e=0;e<8;e++){
        int c = hi*64 + j*8 + e;
        float x = ((float)v[e] - smu[c]) * srs[c];
        o[e] = (_Float16)(x > 0.f ? x : 0.f);
      }
      *(f16x8*)&hs[p][hi*64 + j*8] = o;
    }
    __syncthreads();
  }

  f32x4 acc[4][4];
  #pragma unroll
  for (int i=0;i<4;i++)
    #pragma unroll
    for (int c=0;c<4;c++){ acc[i][c][0]=0.f; acc[i][c][1]=0.f; acc[i][c][2]=0.f; acc[i][c][3]=0.f; }

  for (int k0=0; k0<KCP; k0+=32){
    {
      int o = t>>1, half = t&1;
      f16x8 w0, w1;
      #pragma unroll
      for (int jj=0;jj<8;jj++){
        int c0 = k0 + half*16 + jj, c1 = c0 + 8;
        w0[jj] = (_Float16)((c0<KC) ? ldin(W, (size_t)o*KC + c0, f32) : 0.f);
        w1[jj] = (_Float16)((c1<KC) ? ldin(W, (size_t)o*KC + c1, f32) : 0.f);
      }
      *(f16x8*)&wt[o][half*16]     = w0;
      *(f16x8*)&wt[o][half*16 + 8] = w1;
    }
    __syncthreads();
    f16x8 av[4], bv[4];
    #pragma unroll
    for (int i=0;i<4;i++) av[i] = *(const f16x8*)&hs[wr + i*16 + l16][k0 + q8];
    #pragma unroll
    for (int c=0;c<4;c++) bv[c] = *(const f16x8*)&wt[wc + c*16 + l16][q8];
    #pragma unroll
    for (int i=0;i<4;i++)
      #pragma unroll
      for (int c=0;c<4;c++)
        acc[i][c] = __builtin_amdgcn_mfma_f32_16x16x32_f16(av[i], bv[c], acc[i][c], 0,0,0);
    __syncthreads();
  }

  #pragma unroll
  for (int c=0;c<4;c++){
    int o = wc + c*16 + l16;
    float s1=0.f, s2=0.f;
    #pragma unroll
    for (int i=0;i<4;i++){
      int row = wr + i*16 + q*4;
      #pragma unroll
      for (int r=0;r<4;r++){
        float v = acc[i][c][r];
        Hout[(size_t)(m0 + row + r)*128 + o] = (_Float16)v;
        s1 += v; s2 = fmaf(v,v,s2);
      }
    }
    s1 += __shfl_xor(s1, 16, 64); s1 += __shfl_xor(s1, 32, 64);
    s2 += __shfl_xor(s2, 16, 64); s2 += __shfl_xor(s2, 32, 64);
    if (q==0){ red1[w][c*16+l16] = s1; red2[w][c*16+l16] = s2; }
  }
  __syncthreads();
  if (t<128){
    int lo = t & 63, g = (t>>6)*2;
    unsafeAtomicAdd(&gs1[b*128+t], red1[g][lo] + red1[g+1][lo]);
    unsafeAtomicAdd(&gs2[b*128+t], red2[g][lo] + red2[g+1][lo]);
  }
}

// ---------------------------------------------------------------------------
// Final: per (b,s): mu/rs from layer-3 sums, norm+relu, max over K, fc 128->3
// ---------------------------------------------------------------------------
__global__ __launch_bounds__(128) void final_kernel(
    const void* __restrict__ pc1,
    const _Float16* __restrict__ H,
    const float* __restrict__ gp1, const float* __restrict__ gp2,
    const void* __restrict__ fc_w, const void* __restrict__ fc_b,
    void* __restrict__ outv)
{
  int blk = blockIdx.x;       // b*1024+s
  int b = blk>>10, s = blk & 1023;
  int o = threadIdx.x;
  const bool f32 = detect_f32((const unsigned short*)pc1);
  int bo = b*128 + o;
  const float inv = 1.0f/32768.0f;
  float mu_ = gp1[bo]*inv;
  float rs_ = rsqrtf(gp2[bo]*inv - mu_*mu_ + 1e-5f);
  const _Float16* hp = H + (size_t)blk*NK*128 + o;
  float m = -1e30f;
  #pragma unroll 4
  for(int k=0;k<NK;k++){
    float v = ((float)hp[(size_t)k*128] - mu_)*rs_;
    m = fmaxf(m, v);
  }
  m = fmaxf(m, 0.f);
  __shared__ float mv[128];
  mv[o] = m;
  __syncthreads();
  if (o<3){
    float acc = ldin(fc_b, o, f32);
    for(int c=0;c<128;c++) acc = fmaf(ldin(fc_w, (size_t)o*128+c, f32), mv[c], acc);
    size_t oi = ((size_t)b*3 + o)*NS + s;
    if (f32) ((float*)outv)[oi] = acc;
    else     ((unsigned short*)outv)[oi] = f2bf(acc);
  }
}

// ---------------------------------------------------------------------------
extern "C" void kernel_launch(void* const* d_in, const int* in_sizes, int n_in,
                              void* d_out, int out_size, void* d_ws, size_t ws_size,
                              hipStream_t stream){
  const void* pc1   = d_in[0];
  const void* feats = d_in[1];
  const void* W1    = d_in[2];
  const void* W2    = d_in[4];
  const void* W3    = d_in[6];
  const void* fcw   = d_in[8];
  const void* fcb   = d_in[9];
  char* ws = (char*)d_ws;
  int*      fps  = (int*)     (ws + 0);          // 32768 B
  float*    nxyz = (float*)   (ws + 32768);      // 98304 B
  int*      knn  = (int*)     (ws + 131072);     // 1048576 B
  float*    st   = (float*)   (ws + 1179648);    // 6*1024*4 = 24576 B  [s1a s2a s1b s2b s1c s2c]
  _Float16* Ha   = (_Float16*)(ws + 1204224);    // 67108864 B
  _Float16* Hb   = (_Float16*)(ws + 68313088);   // 67108864 B (total 135421952)
  _Float16* G    = Hb;  // G (8.9 MB) aliases Hb: read only by conv1, Hb first written by conv2

  feat_transpose<<<NB*64, 256, 0, stream>>>(feats, pc1, G, st);
  fps_kernel<<<NB, 256, 0, stream>>>(pc1, fps);
  knn_kernel<<<NB*NS, 256, 0, stream>>>(pc1, fps, nxyz, knn);

  conv_mfma<1><<<NM/128, 256, 0, stream>>>(pc1, G, knn, nxyz,
      (const _Float16*)nullptr, (const float*)nullptr, (const float*)nullptr,
      W1, Ha, st, st+1024);
  conv_mfma<2><<<NM/128, 256, 0, stream>>>(pc1, G, knn, nxyz,
      Ha, st, st+1024, W2, Hb, st+2048, st+3072);
  conv_mfma<3><<<NM/128, 256, 0, stream>>>(pc1, G, knn, nxyz,
      Hb, st+2048, st+3072, W3, Ha, st+4096, st+5120);

  final_kernel<<<NB*NS, 128, 0, stream>>>(pc1, Ha, st+4096, st+5120, fcw, fcb, d_out);
}